// Round 9
// baseline (787.347 us; speedup 1.0000x reference)
//
#include <hip/hip_runtime.h>
#include <hip/hip_fp16.h>

#define BB 32
#define SS 512
#define HH 128
#define D2 256
#define D3 384
#define D4 512

// ws layout (float offsets)
#define OFF_TK  0                       // Ek = exp(2*keyp) TRANSPOSED [B][H][S] f32
#define OFF_TQ  (OFF_TK + BB*SS*HH)     // Eq = exp(2*q)    [B][S][H] f32
#define OFF_CT  (OFF_TQ + BB*SS*HH)     // context   [B][S][2H] f32
#define OFF_GI  (OFF_CT + BB*SS*D2)     // gi        [B][S][3H] f32
#define OFF_F16 (OFF_GI + BB*SS*D3)     // f16 weight region below (element offsets)
#define F16_WG  0                       // Wg  f16 [512][512] row-major (as given)
#define F16_WIH (F16_WG + D4*D4)        // Wih f16 [384][512]
#define F16_W2  (F16_WIH + D3*D4)       // [WvP;WvPt] f16 [256][256]

typedef _Float16 f16x8 __attribute__((ext_vector_type(8)));
typedef _Float16 f16x4 __attribute__((ext_vector_type(4)));
typedef float    f32x4 __attribute__((ext_vector_type(4)));
typedef _Float16 h2_t  __attribute__((ext_vector_type(2)));

__device__ __forceinline__ float fast_tanh(float x) {
  float ax = fabsf(x);
  float e  = __expf(-2.0f * ax);
  float t  = __fdividef(1.0f - e, 1.0f + e);
  return x < 0.0f ? -t : t;
}
__device__ __forceinline__ float sigm(float x) {
  return __fdividef(1.0f, 1.0f + __expf(-x));
}

// ---------------- K0: convert weights to f16 in ws ----------------
__global__ __launch_bounds__(256) void k0_prep(
    const float* __restrict__ Wg, const float* __restrict__ Wih,
    const float* __restrict__ Wvp, const float* __restrict__ Wvpt,
    float* __restrict__ ws) {
  int i = blockIdx.x * 256 + threadIdx.x;
  _Float16* f16b = (_Float16*)(ws + OFF_F16);
  if (i < D4 * D4) {
    f16b[F16_WG + i] = (_Float16)Wg[i];
  } else if (i < D4 * D4 + D3 * D4) {
    int j = i - D4 * D4;
    f16b[F16_WIH + j] = (_Float16)Wih[j];
  } else {
    int j = i - D4 * D4 - D3 * D4;   // < 65536
    f16b[F16_W2 + j] = (_Float16)(j < HH * D2 ? Wvp[j] : Wvpt[j - HH * D2]);
  }
}

// ---------------- K1: Ek^T / Eq = exp(2 * ([WvP;WvPt] . vp^T)) via MFMA ----------------
__global__ __launch_bounds__(256, 2) void k1_keyq(const float* __restrict__ vp,
                                                  float* __restrict__ ws) {
  __shared__ __align__(16) _Float16 vpH[64 * 256];
  int tid = threadIdx.x;
  int rows0 = blockIdx.x * 64;

  #pragma unroll
  for (int i = 0; i < 8; ++i) {
    int u = tid + i * 256;
    int r = u >> 5, c8 = u & 31;
    const float* src = vp + (size_t)(rows0 + r) * D2 + c8 * 8;
    float4 a = *(const float4*)src;
    float4 b = *(const float4*)(src + 4);
    f16x8 h;
    h[0]=(_Float16)a.x; h[1]=(_Float16)a.y; h[2]=(_Float16)a.z; h[3]=(_Float16)a.w;
    h[4]=(_Float16)b.x; h[5]=(_Float16)b.y; h[6]=(_Float16)b.z; h[7]=(_Float16)b.w;
    *(f16x8*)(&vpH[r * 256 + (c8 ^ (r & 7)) * 8]) = h;
  }
  __syncthreads();

  const _Float16* W2 = (const _Float16*)(ws + OFF_F16) + F16_W2;
  int w = tid >> 6, l = tid & 63;
  int lr = l & 15, lk = (l >> 4) * 8;

  f32x4 acc[4][4];
  #pragma unroll
  for (int m = 0; m < 4; ++m)
    #pragma unroll
    for (int n = 0; n < 4; ++n) acc[m][n] = (f32x4){0.f, 0.f, 0.f, 0.f};

  for (int kc = 0; kc < 8; ++kc) {
    int k = kc * 32 + lk;
    f16x8 bf[4];
    #pragma unroll
    for (int n = 0; n < 4; ++n) {
      int r = n * 16 + lr;
      bf[n] = *(const f16x8*)(&vpH[r * 256 + (((k >> 3) ^ (r & 7))) * 8]);
    }
    #pragma unroll
    for (int m = 0; m < 4; ++m) {
      int c = w * 64 + m * 16 + lr;
      f16x8 af = *(const f16x8*)(W2 + (size_t)c * 256 + k);
      #pragma unroll
      for (int n = 0; n < 4; ++n)
        acc[m][n] = __builtin_amdgcn_mfma_f32_16x16x32_f16(af, bf[n], acc[m][n], 0, 0, 0);
    }
  }

  int b = rows0 >> 9;          // batch
  int s0 = rows0 & 511;        // s offset within batch
  float* ekT = ws + OFF_TK + (size_t)b * HH * SS;
  float* eqp = ws + OFF_TQ + (size_t)b * SS * HH;
  #pragma unroll
  for (int m = 0; m < 4; ++m) {
    int c0 = w * 64 + m * 16 + (l >> 4) * 4;
    #pragma unroll
    for (int n = 0; n < 4; ++n) {
      int s = s0 + n * 16 + lr;
      float v[4];
      #pragma unroll
      for (int j = 0; j < 4; ++j) {
        float z = fminf(fmaxf(2.0f * acc[m][n][j], -60.0f), 60.0f);
        v[j] = __expf(z);
      }
      if (c0 < HH) {
        // Ek transposed: [h][s]
        #pragma unroll
        for (int j = 0; j < 4; ++j)
          ekT[(size_t)(c0 + j) * SS + s] = v[j];
      } else {
        float4 o; o.x = v[0]; o.y = v[1]; o.z = v[2]; o.w = v[3];
        *(float4*)(eqp + (size_t)s * HH + (c0 - HH)) = o;
      }
    }
  }
}

// ---------------- K2: logits via exp-form tanh + softmax + ct ----------------
// 1-D grid 1024 blocks: bid = [t:5][q:2][xcd:3]; all 32 t-tiles of batch b
// share one XCD (b = xcd*4+q keeps bid%8 constant per b).
__global__ __launch_bounds__(256) void k2_attn(const float* __restrict__ vp,
                                               const int* __restrict__ lens,
                                               const float* __restrict__ wvt,
                                               float* __restrict__ ws) {
  int bid = blockIdx.x;                 // 0..1023
  int b  = (bid & 7) * 4 + ((bid >> 3) & 3);
  int t0 = (bid >> 5) * 16;             // 0..496
  int len = lens[b];
  if (t0 >= len) return;
  int nt = min(16, len - t0);

  __shared__ float L[16][SS];           // 32KB
  __shared__ float Eqs[16][HH];         // 8KB
  __shared__ float inv_sum[16];

  int tid = threadIdx.x;
  const float* EkT = ws + OFF_TK + (size_t)b * HH * SS;
  const float* Eq  = ws + OFF_TQ + (size_t)b * SS * HH;

  for (int idx = tid; idx < 16 * HH; idx += 256) {
    int i = idx >> 7, h = idx & 127;
    Eqs[i][h] = Eq[(size_t)(t0 + i) * HH + h];
  }
  __syncthreads();

  // logits: tanh(k+q) = 1 - 2/(Ek*Eq+1); softmax shift-invariance drops the
  // constant sum(w) term -> L = -2 * sum_h w_h * rcp(Ek*Eq+1)
  for (int sc = 0; sc < 2; ++sc) {
    int s = tid + sc * 256;
    if (s < len) {
      float acc[16] = {};
      for (int h4 = 0; h4 < 32; ++h4) {
        float k0 = EkT[(size_t)(h4 * 4 + 0) * SS + s];
        float k1 = EkT[(size_t)(h4 * 4 + 1) * SS + s];
        float k2v = EkT[(size_t)(h4 * 4 + 2) * SS + s];
        float k3 = EkT[(size_t)(h4 * 4 + 3) * SS + s];
        const float4 w4 = *(const float4*)(wvt + h4 * 4);
        #pragma unroll
        for (int t = 0; t < 16; ++t) {
          const float4 q4 = *(const float4*)(&Eqs[t][h4 * 4]);
          float r0 = __builtin_amdgcn_rcpf(fmaf(k0, q4.x, 1.0f));
          float r1 = __builtin_amdgcn_rcpf(fmaf(k1, q4.y, 1.0f));
          float r2 = __builtin_amdgcn_rcpf(fmaf(k2v, q4.z, 1.0f));
          float r3 = __builtin_amdgcn_rcpf(fmaf(k3, q4.w, 1.0f));
          float a = acc[t];
          a = fmaf(w4.x, r0, a);
          a = fmaf(w4.y, r1, a);
          a = fmaf(w4.z, r2, a);
          a = fmaf(w4.w, r3, a);
          acc[t] = a;
        }
      }
      #pragma unroll
      for (int t = 0; t < 16; ++t) L[t][s] = -2.0f * acc[t];
    }
  }
  __syncthreads();

  // softmax (store unnormalized exp; denominators in inv_sum)
  {
    int w = tid >> 6, lane = tid & 63;
    for (int ii = 0; ii < 4; ++ii) {
      int i = w + ii * 4;
      if (i < nt) {
        float m = -1e30f;
        for (int s = lane; s < len; s += 64) m = fmaxf(m, L[i][s]);
        #pragma unroll
        for (int off = 32; off > 0; off >>= 1) m = fmaxf(m, __shfl_xor(m, off));
        float sm = 0.0f;
        for (int s = lane; s < len; s += 64) {
          float e = __expf(L[i][s] - m);
          L[i][s] = e;
          sm += e;
        }
        #pragma unroll
        for (int off = 32; off > 0; off >>= 1) sm += __shfl_xor(sm, off);
        if (lane == 0) inv_sum[i] = __fdividef(1.0f, sm);
      }
    }
  }
  __syncthreads();

  // ct[t][d] = sum_s p[t][s] * vp[b][s][d]   (vp direct from L2, no LDS staging)
  int d4 = (tid & 63) * 4;
  int tg = tid >> 6;
  float4 acc4[4] = {};
  const float* vpb = vp + (size_t)b * SS * D2;
  int s = 0;
  for (; s + 4 <= len; s += 4) {
    #pragma unroll
    for (int u = 0; u < 4; ++u) {
      float4 v4 = *(const float4*)(vpb + (size_t)(s + u) * D2 + d4);
      #pragma unroll
      for (int j = 0; j < 4; ++j) {
        float p = L[tg * 4 + j][s + u];
        acc4[j].x = fmaf(p, v4.x, acc4[j].x);
        acc4[j].y = fmaf(p, v4.y, acc4[j].y);
        acc4[j].z = fmaf(p, v4.z, acc4[j].z);
        acc4[j].w = fmaf(p, v4.w, acc4[j].w);
      }
    }
  }
  for (; s < len; ++s) {
    float4 v4 = *(const float4*)(vpb + (size_t)s * D2 + d4);
    #pragma unroll
    for (int j = 0; j < 4; ++j) {
      float p = L[tg * 4 + j][s];
      acc4[j].x = fmaf(p, v4.x, acc4[j].x);
      acc4[j].y = fmaf(p, v4.y, acc4[j].y);
      acc4[j].z = fmaf(p, v4.z, acc4[j].z);
      acc4[j].w = fmaf(p, v4.w, acc4[j].w);
    }
  }
  float* ctg = ws + OFF_CT + ((size_t)b * SS + t0) * D2;
  #pragma unroll
  for (int j = 0; j < 4; ++j) {
    int t = tg * 4 + j;
    if (t < nt) {
      float is = inv_sum[t];
      float4 o;
      o.x = acc4[j].x * is; o.y = acc4[j].y * is;
      o.z = acc4[j].z * is; o.w = acc4[j].w * is;
      *(float4*)(ctg + (size_t)t * D2 + d4) = o;
    }
  }
}

// ---------------- K3: gt' = Wg.vpc^T -> xin (in-place LDS) -> gi' = Wih.xin^T ----------------
__global__ __launch_bounds__(256, 2) void k3_gates(const float* __restrict__ vp,
                                                   const int* __restrict__ lens,
                                                   const float* __restrict__ bih,
                                                   float* __restrict__ ws) {
  int b = blockIdx.y;
  int len = lens[b];
  int t0 = blockIdx.x * 32;
  if (t0 >= len) return;

  __shared__ __align__(16) _Float16 vpcH[32 * 512];
  int tid = threadIdx.x;
  const float* ct = ws + OFF_CT;

  #pragma unroll
  for (int i = 0; i < 8; ++i) {
    int u = tid + i * 256;
    int r = u >> 6, c8 = u & 63;
    int c = c8 * 8;
    const float* src = (c < D2) ? (vp + ((size_t)b * SS + t0 + r) * D2 + c)
                                : (ct + ((size_t)b * SS + t0 + r) * D2 + (c - D2));
    float4 a = *(const float4*)src;
    float4 bb = *(const float4*)(src + 4);
    f16x8 h;
    h[0]=(_Float16)a.x;  h[1]=(_Float16)a.y;  h[2]=(_Float16)a.z;  h[3]=(_Float16)a.w;
    h[4]=(_Float16)bb.x; h[5]=(_Float16)bb.y; h[6]=(_Float16)bb.z; h[7]=(_Float16)bb.w;
    *(f16x8*)(&vpcH[r * 512 + (c8 ^ (r & 7)) * 8]) = h;
  }
  __syncthreads();

  const _Float16* WgH  = (const _Float16*)(ws + OFF_F16) + F16_WG;
  const _Float16* WihH = (const _Float16*)(ws + OFF_F16) + F16_WIH;
  int w = tid >> 6, l = tid & 63;
  int lr = l & 15, lk = (l >> 4) * 8;

  f32x4 acc[8][2];
  #pragma unroll
  for (int m = 0; m < 8; ++m) { acc[m][0] = (f32x4){0.f,0.f,0.f,0.f}; acc[m][1] = (f32x4){0.f,0.f,0.f,0.f}; }

  for (int kc = 0; kc < 16; ++kc) {
    int k = kc * 32 + lk;
    f16x8 bf[2];
    #pragma unroll
    for (int n = 0; n < 2; ++n) {
      int r = n * 16 + lr;
      bf[n] = *(const f16x8*)(&vpcH[r * 512 + (((k >> 3) ^ (r & 7))) * 8]);
    }
    #pragma unroll
    for (int m = 0; m < 8; ++m) {
      int c = w * 128 + m * 16 + lr;
      f16x8 af = *(const f16x8*)(WgH + (size_t)c * 512 + k);
      acc[m][0] = __builtin_amdgcn_mfma_f32_16x16x32_f16(af, bf[0], acc[m][0], 0, 0, 0);
      acc[m][1] = __builtin_amdgcn_mfma_f32_16x16x32_f16(af, bf[1], acc[m][1], 0, 0, 0);
    }
  }

  f16x4 xq[8][2];
  #pragma unroll
  for (int m = 0; m < 8; ++m) {
    int c0 = w * 128 + m * 16 + (l >> 4) * 4;
    #pragma unroll
    for (int n = 0; n < 2; ++n) {
      int r = n * 16 + lr;
      int ea = r * 512 + (((c0 >> 3) ^ (r & 7))) * 8 + (c0 & 7);
      f16x4 vq = *(const f16x4*)(&vpcH[ea]);
      f16x4 xo;
      #pragma unroll
      for (int j = 0; j < 4; ++j)
        xo[j] = (_Float16)(sigm(acc[m][n][j]) * (float)vq[j]);
      xq[m][n] = xo;
    }
  }
  __syncthreads();
  #pragma unroll
  for (int m = 0; m < 8; ++m) {
    int c0 = w * 128 + m * 16 + (l >> 4) * 4;
    #pragma unroll
    for (int n = 0; n < 2; ++n) {
      int r = n * 16 + lr;
      int ea = r * 512 + (((c0 >> 3) ^ (r & 7))) * 8 + (c0 & 7);
      *(f16x4*)(&vpcH[ea]) = xq[m][n];
    }
  }
  __syncthreads();

  f32x4 gacc[6][2];
  #pragma unroll
  for (int m = 0; m < 6; ++m) { gacc[m][0] = (f32x4){0.f,0.f,0.f,0.f}; gacc[m][1] = (f32x4){0.f,0.f,0.f,0.f}; }

  for (int kc = 0; kc < 16; ++kc) {
    int k = kc * 32 + lk;
    f16x8 bf[2];
    #pragma unroll
    for (int n = 0; n < 2; ++n) {
      int r = n * 16 + lr;
      bf[n] = *(const f16x8*)(&vpcH[r * 512 + (((k >> 3) ^ (r & 7))) * 8]);
    }
    #pragma unroll
    for (int m = 0; m < 6; ++m) {
      int c = w * 96 + m * 16 + lr;
      f16x8 af = *(const f16x8*)(WihH + (size_t)c * 512 + k);
      gacc[m][0] = __builtin_amdgcn_mfma_f32_16x16x32_f16(af, bf[0], gacc[m][0], 0, 0, 0);
      gacc[m][1] = __builtin_amdgcn_mfma_f32_16x16x32_f16(af, bf[1], gacc[m][1], 0, 0, 0);
    }
  }

  float* gig = ws + OFF_GI;
  #pragma unroll
  for (int m = 0; m < 6; ++m) {
    int c0 = w * 96 + m * 16 + (l >> 4) * 4;
    float4 bq = *(const float4*)(bih + c0);
    #pragma unroll
    for (int n = 0; n < 2; ++n) {
      int r = n * 16 + lr;
      float4 o;
      o.x = gacc[m][n][0] + bq.x;
      o.y = gacc[m][n][1] + bq.y;
      o.z = gacc[m][n][2] + bq.z;
      o.w = gacc[m][n][3] + bq.w;
      *(float4*)(gig + ((size_t)b * SS + t0 + r) * D3 + c0) = o;
    }
  }
}

// ---------------- K4: GRU scan. 256 threads (4 waves, 1/SIMD) process BOTH
// directions of batch b in ONE instruction stream (ILP pairing): shared
// weight registers (same unit j), dots(fwd)+dots(rev) issue back-to-back so
// each direction's shfl/gate tail hides under the other's dot issue, and the
// barrier cost is paid once per direction-PAIR. Pair-split K (lane: unit
// j=32w+(l&31), half p=l>>5), 96 weight VGPRs, shfl_xor(32) combine,
// double-buffered hbuf per dir, depth-4 gi prefetch. ----------
__global__ __launch_bounds__(256, 1) void k4_scan(const float* __restrict__ whh,
                                                  const float* __restrict__ bhh,
                                                  const int* __restrict__ lens,
                                                  const float* __restrict__ ws,
                                                  float* __restrict__ out) {
  int bid = blockIdx.x;               // 0..31
  int b = (bid & 7) * 4 + (bid >> 3); // XCD swizzle: 4 batches per XCD
  int len = lens[b];
  int tid = threadIdx.x;              // 0..255
  int wv = tid >> 6, l = tid & 63;
  int j = wv * 32 + (l & 31);         // hidden unit 0..127
  int p = l >> 5;                     // K-half 0/1
  const float* gi = ws + OFF_GI + (size_t)b * SS * D3;

  // register-resident: 3 W_hh rows (r,z,n for unit j), K range [p*64, p*64+64)
  h2_t w0[32], w1[32], w2[32];
  {
    const float* r0 = whh + (size_t)j * HH + p * 64;
    const float* r1 = whh + (size_t)(j + 128) * HH + p * 64;
    const float* r2 = whh + (size_t)(j + 256) * HH + p * 64;
    #pragma unroll
    for (int k = 0; k < 32; ++k) {
      w0[k] = h2_t{(_Float16)r0[2 * k], (_Float16)r0[2 * k + 1]};
      w1[k] = h2_t{(_Float16)r1[2 * k], (_Float16)r1[2 * k + 1]};
      w2[k] = h2_t{(_Float16)r2[2 * k], (_Float16)r2[2 * k + 1]};
    }
  }
  float bh0 = bhh[j], bh1 = bhh[j + 128], bh2 = bhh[j + 256];

  __shared__ __align__(16) _Float16 hbuf[2][2][128];   // [dir][parity][unit]
  if (tid < 256) hbuf[tid >> 7][0][tid & 127] = (_Float16)0.0f;
  float hF_own = 0.0f, hR_own = 0.0f;

  float* outF = out + (size_t)b * SS * D2;        // fwd half (dir 0)
  float* outR = outF + HH;                        // rev half (dir 1)

#define K4_BAR() do {                                                          \
    asm volatile("s_waitcnt lgkmcnt(0)" ::: "memory");                         \
    __builtin_amdgcn_s_barrier();                                              \
    __builtin_amdgcn_sched_barrier(0);                                         \
  } while (0)

  // prefetch both dirs' gi rows for step tnext (p==0 lanes only)
#define K4_PF2(fx0, fx1, fx2, rx0, rx1, rx2, tnext) do {                       \
    if (p == 0) {                                                              \
      int tp = (tnext) < len ? (tnext) : (len - 1);                            \
      const float* gf = gi + (size_t)tp * D3;                                  \
      const float* gr = gi + (size_t)(len - 1 - tp) * D3;                      \
      fx0 = gf[j]; fx1 = gf[j + 128]; fx2 = gf[j + 256];                       \
      rx0 = gr[j]; rx1 = gr[j + 128]; rx2 = gr[j + 256];                       \
    }                                                                          \
  } while (0)

  // 96 fdot2 over one dir's h-half -> 3 partial sums (pre-shfl)
#define K4_DOTS(HB, S0, S1, S2) do {                                           \
    const f16x8* hb8_ = (const f16x8*)(HB);                                    \
    float a00 = 0.f, a01 = 0.f, a02 = 0.f, a03 = 0.f;                          \
    float a10 = 0.f, a11 = 0.f, a12 = 0.f, a13 = 0.f;                          \
    float a20 = 0.f, a21 = 0.f, a22 = 0.f, a23 = 0.f;                          \
    _Pragma("unroll")                                                          \
    for (int k8 = 0; k8 < 8; ++k8) {                                           \
      f16x8 hv = hb8_[k8];                                                     \
      h2_t q0 = __builtin_shufflevector(hv, hv, 0, 1);                         \
      h2_t q1 = __builtin_shufflevector(hv, hv, 2, 3);                         \
      h2_t q2 = __builtin_shufflevector(hv, hv, 4, 5);                         \
      h2_t q3 = __builtin_shufflevector(hv, hv, 6, 7);                         \
      a00 = __builtin_amdgcn_fdot2(q0, w0[4 * k8 + 0], a00, false);            \
      a01 = __builtin_amdgcn_fdot2(q1, w0[4 * k8 + 1], a01, false);            \
      a02 = __builtin_amdgcn_fdot2(q2, w0[4 * k8 + 2], a02, false);            \
      a03 = __builtin_amdgcn_fdot2(q3, w0[4 * k8 + 3], a03, false);            \
      a10 = __builtin_amdgcn_fdot2(q0, w1[4 * k8 + 0], a10, false);            \
      a11 = __builtin_amdgcn_fdot2(q1, w1[4 * k8 + 1], a11, false);            \
      a12 = __builtin_amdgcn_fdot2(q2, w1[4 * k8 + 2], a12, false);            \
      a13 = __builtin_amdgcn_fdot2(q3, w1[4 * k8 + 3], a13, false);            \
      a20 = __builtin_amdgcn_fdot2(q0, w2[4 * k8 + 0], a20, false);            \
      a21 = __builtin_amdgcn_fdot2(q1, w2[4 * k8 + 1], a21, false);            \
      a22 = __builtin_amdgcn_fdot2(q2, w2[4 * k8 + 2], a22, false);            \
      a23 = __builtin_amdgcn_fdot2(q3, w2[4 * k8 + 3], a23, false);            \
    }                                                                          \
    S0 = ((a00 + a01) + (a02 + a03));                                          \
    S1 = ((a10 + a11) + (a12 + a13));                                          \
    S2 = ((a20 + a21) + (a22 + a23));                                          \
  } while (0)

#define K4_TAIL(S0, S1, S2, GX0, GX1, GX2, HOWN, OUTB, DIRI, tstep, PB) do {   \
    S0 += __shfl_xor(S0, 32);                                                  \
    S1 += __shfl_xor(S1, 32);                                                  \
    S2 += __shfl_xor(S2, 32);                                                  \
    if (p == 0) {                                                              \
      float r = sigm((GX0) + S0 + bh0);                                        \
      float z = sigm((GX1) + S1 + bh1);                                        \
      float n = fast_tanh(fmaf(r, S2 + bh2, (GX2)));                           \
      float hn = (1.0f - z) * n + z * (HOWN);                                  \
      HOWN = hn;                                                               \
      (OUTB)[(size_t)(tstep) * D2 + j] = hn;                                   \
      hbuf[DIRI][(PB) ^ 1][j] = (_Float16)hn;                                  \
    }                                                                          \
  } while (0)

  // one PAIR step: both dirs' dots issue back-to-back; tails after; 1 barrier.
#define K4_STEP2(fx0, fx1, fx2, rx0, rx1, rx2, tstep, PB) do {                 \
    float sF0, sF1, sF2, sR0, sR1, sR2;                                        \
    K4_DOTS(&hbuf[0][PB][p * 64], sF0, sF1, sF2);                              \
    K4_DOTS(&hbuf[1][PB][p * 64], sR0, sR1, sR2);                              \
    K4_TAIL(sF0, sF1, sF2, fx0, fx1, fx2, hF_own, outF, 0, tstep, PB);         \
    K4_TAIL(sR0, sR1, sR2, rx0, rx1, rx2, hR_own, outR, 1, tstep, PB);         \
    K4_PF2(fx0, fx1, fx2, rx0, rx1, rx2, (tstep) + 4);                         \
    K4_BAR();                                                                  \
  } while (0)

  // prologue: prefetch t=0..3 both dirs (len >= 256 always)
  float fA0 = 0.f, fA1 = 0.f, fA2 = 0.f, rA0 = 0.f, rA1 = 0.f, rA2 = 0.f;
  float fB0 = 0.f, fB1 = 0.f, fB2 = 0.f, rB0 = 0.f, rB1 = 0.f, rB2 = 0.f;
  float fC0 = 0.f, fC1 = 0.f, fC2 = 0.f, rC0 = 0.f, rC1 = 0.f, rC2 = 0.f;
  float fD0 = 0.f, fD1 = 0.f, fD2 = 0.f, rD0 = 0.f, rD1 = 0.f, rD2 = 0.f;
  K4_PF2(fA0, fA1, fA2, rA0, rA1, rA2, 0);
  K4_PF2(fB0, fB1, fB2, rB0, rB1, rB2, 1);
  K4_PF2(fC0, fC1, fC2, rC0, rC1, rC2, 2);
  K4_PF2(fD0, fD1, fD2, rD0, rD1, rD2, 3);
  K4_BAR();   // hbuf init visible; global prefetches stay in flight

  int t = 0;
  while (t + 3 < len) {      // t stays a multiple of 4 -> parities 0,1,0,1
    K4_STEP2(fA0, fA1, fA2, rA0, rA1, rA2, t,     0);
    K4_STEP2(fB0, fB1, fB2, rB0, rB1, rB2, t + 1, 1);
    K4_STEP2(fC0, fC1, fC2, rC0, rC1, rC2, t + 2, 0);
    K4_STEP2(fD0, fD1, fD2, rD0, rD1, rD2, t + 3, 1);
    t += 4;
  }
  if (t < len)     K4_STEP2(fA0, fA1, fA2, rA0, rA1, rA2, t,     0);
  if (t + 1 < len) K4_STEP2(fB0, fB1, fB2, rB0, rB1, rB2, t + 1, 1);
  if (t + 2 < len) K4_STEP2(fC0, fC1, fC2, rC0, rC1, rC2, t + 2, 0);

#undef K4_STEP2
#undef K4_TAIL
#undef K4_DOTS
#undef K4_PF2
#undef K4_BAR
}

extern "C" void kernel_launch(void* const* d_in, const int* in_sizes, int n_in,
                              void* d_out, int out_size, void* d_ws, size_t ws_size,
                              hipStream_t stream) {
  const float* vp   = (const float*)d_in[0];
  const int*   lens = (const int*)d_in[1];
  const float* Wvp  = (const float*)d_in[2];
  const float* Wvpt = (const float*)d_in[3];
  const float* wvt  = (const float*)d_in[4];
  const float* Wg   = (const float*)d_in[5];
  const float* Wih  = (const float*)d_in[6];
  const float* Whh  = (const float*)d_in[7];
  const float* bih  = (const float*)d_in[8];
  const float* bhh  = (const float*)d_in[9];
  float* out = (float*)d_out;
  float* ws  = (float*)d_ws;

  hipMemsetAsync(d_out, 0, (size_t)out_size * sizeof(float), stream);

  k0_prep<<<2048, 256, 0, stream>>>(Wg, Wih, Wvp, Wvpt, ws);
  k1_keyq<<<BB * SS / 64, 256, 0, stream>>>(vp, ws);
  k2_attn<<<1024, 256, 0, stream>>>(vp, lens, wvt, ws);
  k3_gates<<<dim3(SS / 32, BB), 256, 0, stream>>>(vp, lens, bih, ws);
  k4_scan<<<32, 256, 0, stream>>>(Whh, bhh, lens, ws, out);
}

// Round 10
// 786.518 us; speedup vs baseline: 1.0011x; 1.0011x over previous
//
#include <hip/hip_runtime.h>
#include <hip/hip_fp16.h>

#define BB 32
#define SS 512
#define HH 128
#define D2 256
#define D3 384
#define D4 512

// ws layout (float offsets)
#define OFF_TK  0                       // Ek = exp(2*keyp) TRANSPOSED [B][H][S] f32
#define OFF_TQ  (OFF_TK + BB*SS*HH)     // Eq = exp(2*q)    [B][S][H] f32
#define OFF_CT  (OFF_TQ + BB*SS*HH)     // context   [B][S][2H] f32
#define OFF_GI  (OFF_CT + BB*SS*D2)     // gi        [B][S][3H] f32
#define OFF_F16 (OFF_GI + BB*SS*D3)     // f16 weight region below (element offsets)
#define F16_WG  0                       // Wg  f16 [512][512] row-major (as given)
#define F16_WIH (F16_WG + D4*D4)        // Wih f16 [384][512]
#define F16_W2  (F16_WIH + D3*D4)       // [WvP;WvPt] f16 [256][256]

typedef _Float16 f16x8 __attribute__((ext_vector_type(8)));
typedef _Float16 f16x4 __attribute__((ext_vector_type(4)));
typedef float    f32x4 __attribute__((ext_vector_type(4)));
typedef _Float16 h2_t  __attribute__((ext_vector_type(2)));

__device__ __forceinline__ float fast_tanh(float x) {
  float ax = fabsf(x);
  float e  = __expf(-2.0f * ax);
  float t  = __fdividef(1.0f - e, 1.0f + e);
  return x < 0.0f ? -t : t;
}
__device__ __forceinline__ float sigm(float x) {
  return __fdividef(1.0f, 1.0f + __expf(-x));
}

// ---------------- K0: convert weights to f16 in ws ----------------
__global__ __launch_bounds__(256) void k0_prep(
    const float* __restrict__ Wg, const float* __restrict__ Wih,
    const float* __restrict__ Wvp, const float* __restrict__ Wvpt,
    float* __restrict__ ws) {
  int i = blockIdx.x * 256 + threadIdx.x;
  _Float16* f16b = (_Float16*)(ws + OFF_F16);
  if (i < D4 * D4) {
    f16b[F16_WG + i] = (_Float16)Wg[i];
  } else if (i < D4 * D4 + D3 * D4) {
    int j = i - D4 * D4;
    f16b[F16_WIH + j] = (_Float16)Wih[j];
  } else {
    int j = i - D4 * D4 - D3 * D4;   // < 65536
    f16b[F16_W2 + j] = (_Float16)(j < HH * D2 ? Wvp[j] : Wvpt[j - HH * D2]);
  }
}

// ---------------- K1: Ek^T / Eq = exp(2 * ([WvP;WvPt] . vp^T)) via MFMA ----------------
__global__ __launch_bounds__(256, 2) void k1_keyq(const float* __restrict__ vp,
                                                  float* __restrict__ ws) {
  __shared__ __align__(16) _Float16 vpH[64 * 256];
  int tid = threadIdx.x;
  int rows0 = blockIdx.x * 64;

  #pragma unroll
  for (int i = 0; i < 8; ++i) {
    int u = tid + i * 256;
    int r = u >> 5, c8 = u & 31;
    const float* src = vp + (size_t)(rows0 + r) * D2 + c8 * 8;
    float4 a = *(const float4*)src;
    float4 b = *(const float4*)(src + 4);
    f16x8 h;
    h[0]=(_Float16)a.x; h[1]=(_Float16)a.y; h[2]=(_Float16)a.z; h[3]=(_Float16)a.w;
    h[4]=(_Float16)b.x; h[5]=(_Float16)b.y; h[6]=(_Float16)b.z; h[7]=(_Float16)b.w;
    *(f16x8*)(&vpH[r * 256 + (c8 ^ (r & 7)) * 8]) = h;
  }
  __syncthreads();

  const _Float16* W2 = (const _Float16*)(ws + OFF_F16) + F16_W2;
  int w = tid >> 6, l = tid & 63;
  int lr = l & 15, lk = (l >> 4) * 8;

  f32x4 acc[4][4];
  #pragma unroll
  for (int m = 0; m < 4; ++m)
    #pragma unroll
    for (int n = 0; n < 4; ++n) acc[m][n] = (f32x4){0.f, 0.f, 0.f, 0.f};

  for (int kc = 0; kc < 8; ++kc) {
    int k = kc * 32 + lk;
    f16x8 bf[4];
    #pragma unroll
    for (int n = 0; n < 4; ++n) {
      int r = n * 16 + lr;
      bf[n] = *(const f16x8*)(&vpH[r * 256 + (((k >> 3) ^ (r & 7))) * 8]);
    }
    #pragma unroll
    for (int m = 0; m < 4; ++m) {
      int c = w * 64 + m * 16 + lr;
      f16x8 af = *(const f16x8*)(W2 + (size_t)c * 256 + k);
      #pragma unroll
      for (int n = 0; n < 4; ++n)
        acc[m][n] = __builtin_amdgcn_mfma_f32_16x16x32_f16(af, bf[n], acc[m][n], 0, 0, 0);
    }
  }

  int b = rows0 >> 9;          // batch
  int s0 = rows0 & 511;        // s offset within batch
  float* ekT = ws + OFF_TK + (size_t)b * HH * SS;
  float* eqp = ws + OFF_TQ + (size_t)b * SS * HH;
  #pragma unroll
  for (int m = 0; m < 4; ++m) {
    int c0 = w * 64 + m * 16 + (l >> 4) * 4;
    #pragma unroll
    for (int n = 0; n < 4; ++n) {
      int s = s0 + n * 16 + lr;
      float v[4];
      #pragma unroll
      for (int j = 0; j < 4; ++j) {
        float z = fminf(fmaxf(2.0f * acc[m][n][j], -60.0f), 60.0f);
        v[j] = __expf(z);
      }
      if (c0 < HH) {
        // Ek transposed: [h][s]
        #pragma unroll
        for (int j = 0; j < 4; ++j)
          ekT[(size_t)(c0 + j) * SS + s] = v[j];
      } else {
        float4 o; o.x = v[0]; o.y = v[1]; o.z = v[2]; o.w = v[3];
        *(float4*)(eqp + (size_t)s * HH + (c0 - HH)) = o;
      }
    }
  }
}

// ---------------- K2: logits via exp-form tanh + softmax + ct ----------------
__global__ __launch_bounds__(256) void k2_attn(const float* __restrict__ vp,
                                               const int* __restrict__ lens,
                                               const float* __restrict__ wvt,
                                               float* __restrict__ ws) {
  int bid = blockIdx.x;                 // 0..1023
  int b  = (bid & 7) * 4 + ((bid >> 3) & 3);
  int t0 = (bid >> 5) * 16;             // 0..496
  int len = lens[b];
  if (t0 >= len) return;
  int nt = min(16, len - t0);

  __shared__ float L[16][SS];           // 32KB
  __shared__ float Eqs[16][HH];         // 8KB
  __shared__ float inv_sum[16];

  int tid = threadIdx.x;
  const float* EkT = ws + OFF_TK + (size_t)b * HH * SS;
  const float* Eq  = ws + OFF_TQ + (size_t)b * SS * HH;

  for (int idx = tid; idx < 16 * HH; idx += 256) {
    int i = idx >> 7, h = idx & 127;
    Eqs[i][h] = Eq[(size_t)(t0 + i) * HH + h];
  }
  __syncthreads();

  for (int sc = 0; sc < 2; ++sc) {
    int s = tid + sc * 256;
    if (s < len) {
      float acc[16] = {};
      for (int h4 = 0; h4 < 32; ++h4) {
        float k0 = EkT[(size_t)(h4 * 4 + 0) * SS + s];
        float k1 = EkT[(size_t)(h4 * 4 + 1) * SS + s];
        float k2v = EkT[(size_t)(h4 * 4 + 2) * SS + s];
        float k3 = EkT[(size_t)(h4 * 4 + 3) * SS + s];
        const float4 w4 = *(const float4*)(wvt + h4 * 4);
        #pragma unroll
        for (int t = 0; t < 16; ++t) {
          const float4 q4 = *(const float4*)(&Eqs[t][h4 * 4]);
          float r0 = __builtin_amdgcn_rcpf(fmaf(k0, q4.x, 1.0f));
          float r1 = __builtin_amdgcn_rcpf(fmaf(k1, q4.y, 1.0f));
          float r2 = __builtin_amdgcn_rcpf(fmaf(k2v, q4.z, 1.0f));
          float r3 = __builtin_amdgcn_rcpf(fmaf(k3, q4.w, 1.0f));
          float a = acc[t];
          a = fmaf(w4.x, r0, a);
          a = fmaf(w4.y, r1, a);
          a = fmaf(w4.z, r2, a);
          a = fmaf(w4.w, r3, a);
          acc[t] = a;
        }
      }
      #pragma unroll
      for (int t = 0; t < 16; ++t) L[t][s] = -2.0f * acc[t];
    }
  }
  __syncthreads();

  {
    int w = tid >> 6, lane = tid & 63;
    for (int ii = 0; ii < 4; ++ii) {
      int i = w + ii * 4;
      if (i < nt) {
        float m = -1e30f;
        for (int s = lane; s < len; s += 64) m = fmaxf(m, L[i][s]);
        #pragma unroll
        for (int off = 32; off > 0; off >>= 1) m = fmaxf(m, __shfl_xor(m, off));
        float sm = 0.0f;
        for (int s = lane; s < len; s += 64) {
          float e = __expf(L[i][s] - m);
          L[i][s] = e;
          sm += e;
        }
        #pragma unroll
        for (int off = 32; off > 0; off >>= 1) sm += __shfl_xor(sm, off);
        if (lane == 0) inv_sum[i] = __fdividef(1.0f, sm);
      }
    }
  }
  __syncthreads();

  int d4 = (tid & 63) * 4;
  int tg = tid >> 6;
  float4 acc4[4] = {};
  const float* vpb = vp + (size_t)b * SS * D2;
  int s = 0;
  for (; s + 4 <= len; s += 4) {
    #pragma unroll
    for (int u = 0; u < 4; ++u) {
      float4 v4 = *(const float4*)(vpb + (size_t)(s + u) * D2 + d4);
      #pragma unroll
      for (int j = 0; j < 4; ++j) {
        float p = L[tg * 4 + j][s + u];
        acc4[j].x = fmaf(p, v4.x, acc4[j].x);
        acc4[j].y = fmaf(p, v4.y, acc4[j].y);
        acc4[j].z = fmaf(p, v4.z, acc4[j].z);
        acc4[j].w = fmaf(p, v4.w, acc4[j].w);
      }
    }
  }
  for (; s < len; ++s) {
    float4 v4 = *(const float4*)(vpb + (size_t)s * D2 + d4);
    #pragma unroll
    for (int j = 0; j < 4; ++j) {
      float p = L[tg * 4 + j][s];
      acc4[j].x = fmaf(p, v4.x, acc4[j].x);
      acc4[j].y = fmaf(p, v4.y, acc4[j].y);
      acc4[j].z = fmaf(p, v4.z, acc4[j].z);
      acc4[j].w = fmaf(p, v4.w, acc4[j].w);
    }
  }
  float* ctg = ws + OFF_CT + ((size_t)b * SS + t0) * D2;
  #pragma unroll
  for (int j = 0; j < 4; ++j) {
    int t = tg * 4 + j;
    if (t < nt) {
      float is = inv_sum[t];
      float4 o;
      o.x = acc4[j].x * is; o.y = acc4[j].y * is;
      o.z = acc4[j].z * is; o.w = acc4[j].w * is;
      *(float4*)(ctg + (size_t)t * D2 + d4) = o;
    }
  }
}

// ---------------- K3: gt' = Wg.vpc^T -> xin (in-place LDS) -> gi' = Wih.xin^T ----------------
__global__ __launch_bounds__(256, 2) void k3_gates(const float* __restrict__ vp,
                                                   const int* __restrict__ lens,
                                                   const float* __restrict__ bih,
                                                   float* __restrict__ ws) {
  int b = blockIdx.y;
  int len = lens[b];
  int t0 = blockIdx.x * 32;
  if (t0 >= len) return;

  __shared__ __align__(16) _Float16 vpcH[32 * 512];
  int tid = threadIdx.x;
  const float* ct = ws + OFF_CT;

  #pragma unroll
  for (int i = 0; i < 8; ++i) {
    int u = tid + i * 256;
    int r = u >> 6, c8 = u & 63;
    int c = c8 * 8;
    const float* src = (c < D2) ? (vp + ((size_t)b * SS + t0 + r) * D2 + c)
                                : (ct + ((size_t)b * SS + t0 + r) * D2 + (c - D2));
    float4 a = *(const float4*)src;
    float4 bb = *(const float4*)(src + 4);
    f16x8 h;
    h[0]=(_Float16)a.x;  h[1]=(_Float16)a.y;  h[2]=(_Float16)a.z;  h[3]=(_Float16)a.w;
    h[4]=(_Float16)bb.x; h[5]=(_Float16)bb.y; h[6]=(_Float16)bb.z; h[7]=(_Float16)bb.w;
    *(f16x8*)(&vpcH[r * 512 + (c8 ^ (r & 7)) * 8]) = h;
  }
  __syncthreads();

  const _Float16* WgH  = (const _Float16*)(ws + OFF_F16) + F16_WG;
  const _Float16* WihH = (const _Float16*)(ws + OFF_F16) + F16_WIH;
  int w = tid >> 6, l = tid & 63;
  int lr = l & 15, lk = (l >> 4) * 8;

  f32x4 acc[8][2];
  #pragma unroll
  for (int m = 0; m < 8; ++m) { acc[m][0] = (f32x4){0.f,0.f,0.f,0.f}; acc[m][1] = (f32x4){0.f,0.f,0.f,0.f}; }

  for (int kc = 0; kc < 16; ++kc) {
    int k = kc * 32 + lk;
    f16x8 bf[2];
    #pragma unroll
    for (int n = 0; n < 2; ++n) {
      int r = n * 16 + lr;
      bf[n] = *(const f16x8*)(&vpcH[r * 512 + (((k >> 3) ^ (r & 7))) * 8]);
    }
    #pragma unroll
    for (int m = 0; m < 8; ++m) {
      int c = w * 128 + m * 16 + lr;
      f16x8 af = *(const f16x8*)(WgH + (size_t)c * 512 + k);
      acc[m][0] = __builtin_amdgcn_mfma_f32_16x16x32_f16(af, bf[0], acc[m][0], 0, 0, 0);
      acc[m][1] = __builtin_amdgcn_mfma_f32_16x16x32_f16(af, bf[1], acc[m][1], 0, 0, 0);
    }
  }

  f16x4 xq[8][2];
  #pragma unroll
  for (int m = 0; m < 8; ++m) {
    int c0 = w * 128 + m * 16 + (l >> 4) * 4;
    #pragma unroll
    for (int n = 0; n < 2; ++n) {
      int r = n * 16 + lr;
      int ea = r * 512 + (((c0 >> 3) ^ (r & 7))) * 8 + (c0 & 7);
      f16x4 vq = *(const f16x4*)(&vpcH[ea]);
      f16x4 xo;
      #pragma unroll
      for (int j = 0; j < 4; ++j)
        xo[j] = (_Float16)(sigm(acc[m][n][j]) * (float)vq[j]);
      xq[m][n] = xo;
    }
  }
  __syncthreads();
  #pragma unroll
  for (int m = 0; m < 8; ++m) {
    int c0 = w * 128 + m * 16 + (l >> 4) * 4;
    #pragma unroll
    for (int n = 0; n < 2; ++n) {
      int r = n * 16 + lr;
      int ea = r * 512 + (((c0 >> 3) ^ (r & 7))) * 8 + (c0 & 7);
      *(f16x4*)(&vpcH[ea]) = xq[m][n];
    }
  }
  __syncthreads();

  f32x4 gacc[6][2];
  #pragma unroll
  for (int m = 0; m < 6; ++m) { gacc[m][0] = (f32x4){0.f,0.f,0.f,0.f}; gacc[m][1] = (f32x4){0.f,0.f,0.f,0.f}; }

  for (int kc = 0; kc < 16; ++kc) {
    int k = kc * 32 + lk;
    f16x8 bf[2];
    #pragma unroll
    for (int n = 0; n < 2; ++n) {
      int r = n * 16 + lr;
      bf[n] = *(const f16x8*)(&vpcH[r * 512 + (((k >> 3) ^ (r & 7))) * 8]);
    }
    #pragma unroll
    for (int m = 0; m < 6; ++m) {
      int c = w * 96 + m * 16 + lr;
      f16x8 af = *(const f16x8*)(WihH + (size_t)c * 512 + k);
      gacc[m][0] = __builtin_amdgcn_mfma_f32_16x16x32_f16(af, bf[0], gacc[m][0], 0, 0, 0);
      gacc[m][1] = __builtin_amdgcn_mfma_f32_16x16x32_f16(af, bf[1], gacc[m][1], 0, 0, 0);
    }
  }

  float* gig = ws + OFF_GI;
  #pragma unroll
  for (int m = 0; m < 6; ++m) {
    int c0 = w * 96 + m * 16 + (l >> 4) * 4;
    float4 bq = *(const float4*)(bih + c0);
    #pragma unroll
    for (int n = 0; n < 2; ++n) {
      int r = n * 16 + lr;
      float4 o;
      o.x = gacc[m][n][0] + bq.x;
      o.y = gacc[m][n][1] + bq.y;
      o.z = gacc[m][n][2] + bq.z;
      o.w = gacc[m][n][3] + bq.w;
      *(float4*)(gig + ((size_t)b * SS + t0 + r) * D3 + c0) = o;
    }
  }
}

// ---------------- K4: batched MFMA GRU scan. 4 blocks x 16 seq (8 b x 2 dir),
// 512 threads = 8 waves. Per step: gh = W_hh(384x128) . H(128x16) via MFMA.
// Wave w owns M-tiles {w, w+8, w+16} -> its C rows are (r,z,n) of units
// [16w,16w+16): gate combine is pure per-lane VALU (NO shuffles). A-frags
// (W_hh f16) register-resident: 48 VGPR. H in LDS [seq][128] f16, XOR-swizzled,
// double-buffered, ONE barrier/step. Depth-4 gi prefetch (dwordx4/lane/group).
// Per-seq active predication handles variable lens (packed semantics). -------
__global__ __launch_bounds__(512, 1) void k4_scan(const float* __restrict__ whh,
                                                  const float* __restrict__ bhh,
                                                  const int* __restrict__ lens,
                                                  const float* __restrict__ ws,
                                                  float* __restrict__ out) {
  int blk = blockIdx.x;              // 0..3
  int tid = threadIdx.x;             // 0..511
  int w = tid >> 6, l = tid & 63;
  int seq = l & 15;                  // 0..15 (column of C / N of B)
  int b_local = seq & 7, dir = seq >> 3;
  int b = blk * 8 + b_local;
  int len = lens[b];
  int maxlen = 0;
  #pragma unroll
  for (int i = 0; i < 8; ++i) {
    int li = lens[blk * 8 + i];
    maxlen = li > maxlen ? li : maxlen;
  }

  int j0 = 16 * w + ((l >> 4) << 2);   // C-row base: units j0..j0+3 (group 0)

  // A-fragments: W_hh rows, f16, register-resident (12 x f16x8 = 48 VGPR)
  f16x8 afr[3][4];
  #pragma unroll
  for (int g = 0; g < 3; ++g) {
    int row = 128 * g + 16 * w + (l & 15);
    #pragma unroll
    for (int kc = 0; kc < 4; ++kc) {
      const float* ap = whh + (size_t)row * HH + kc * 32 + (l >> 4) * 8;
      float4 x = *(const float4*)ap;
      float4 y = *(const float4*)(ap + 4);
      f16x8 f;
      f[0]=(_Float16)x.x; f[1]=(_Float16)x.y; f[2]=(_Float16)x.z; f[3]=(_Float16)x.w;
      f[4]=(_Float16)y.x; f[5]=(_Float16)y.y; f[6]=(_Float16)y.z; f[7]=(_Float16)y.w;
      afr[g][kc] = f;
    }
  }
  f32x4 bh0 = *(const f32x4*)(bhh + 0 * 128 + j0);
  f32x4 bh1 = *(const f32x4*)(bhh + 1 * 128 + j0);
  f32x4 bh2 = *(const f32x4*)(bhh + 2 * 128 + j0);

  // H in LDS: [parity][seq][128] f16, elem swizzle: k ^= (seq&7)<<3
  __shared__ __align__(16) _Float16 hb[2 * 16 * 128];
  for (int i = tid; i < 2048; i += 512) hb[i] = (_Float16)0.0f;  // parity-0 zero

  f32x4 h_own = (f32x4){0.f, 0.f, 0.f, 0.f};
  const float* gi_b = ws + OFF_GI + (size_t)b * SS * D3;
  float* outp = out + (size_t)b * SS * D2 + dir * HH + j0;

#define K4_BAR() do {                                                          \
    asm volatile("s_waitcnt lgkmcnt(0)" ::: "memory");                         \
    __builtin_amdgcn_s_barrier();                                              \
    __builtin_amdgcn_sched_barrier(0);                                         \
  } while (0)

#define K4_PF(GV0, GV1, GV2, tnext) do {                                       \
    int tp = (tnext) < len ? (tnext) : (len - 1);                              \
    int tg = dir ? (len - 1 - tp) : tp;                                        \
    const float* gp = gi_b + (size_t)tg * D3;                                  \
    GV0 = *(const f32x4*)(gp + 0 * 128 + j0);                                  \
    GV1 = *(const f32x4*)(gp + 1 * 128 + j0);                                  \
    GV2 = *(const f32x4*)(gp + 2 * 128 + j0);                                  \
  } while (0)

#define K4_STEP(GV0, GV1, GV2, tstep, PB) do {                                 \
    const _Float16* hbR = hb + (PB) * 2048;                                    \
    f16x8 bf0, bf1, bf2, bf3;                                                  \
    {                                                                          \
      int kb = (l >> 4) * 8;                                                   \
      int sw = (seq & 7) << 3;                                                 \
      bf0 = *(const f16x8*)(hbR + seq * 128 + ((kb +  0) ^ sw));               \
      bf1 = *(const f16x8*)(hbR + seq * 128 + ((kb + 32) ^ sw));               \
      bf2 = *(const f16x8*)(hbR + seq * 128 + ((kb + 64) ^ sw));               \
      bf3 = *(const f16x8*)(hbR + seq * 128 + ((kb + 96) ^ sw));               \
    }                                                                          \
    f32x4 ac0 = (f32x4){0.f,0.f,0.f,0.f};                                      \
    f32x4 ac1 = (f32x4){0.f,0.f,0.f,0.f};                                      \
    f32x4 ac2 = (f32x4){0.f,0.f,0.f,0.f};                                      \
    ac0 = __builtin_amdgcn_mfma_f32_16x16x32_f16(afr[0][0], bf0, ac0, 0,0,0);  \
    ac1 = __builtin_amdgcn_mfma_f32_16x16x32_f16(afr[1][0], bf0, ac1, 0,0,0);  \
    ac2 = __builtin_amdgcn_mfma_f32_16x16x32_f16(afr[2][0], bf0, ac2, 0,0,0);  \
    ac0 = __builtin_amdgcn_mfma_f32_16x16x32_f16(afr[0][1], bf1, ac0, 0,0,0);  \
    ac1 = __builtin_amdgcn_mfma_f32_16x16x32_f16(afr[1][1], bf1, ac1, 0,0,0);  \
    ac2 = __builtin_amdgcn_mfma_f32_16x16x32_f16(afr[2][1], bf1, ac2, 0,0,0);  \
    ac0 = __builtin_amdgcn_mfma_f32_16x16x32_f16(afr[0][2], bf2, ac0, 0,0,0);  \
    ac1 = __builtin_amdgcn_mfma_f32_16x16x32_f16(afr[1][2], bf2, ac1, 0,0,0);  \
    ac2 = __builtin_amdgcn_mfma_f32_16x16x32_f16(afr[2][2], bf2, ac2, 0,0,0);  \
    ac0 = __builtin_amdgcn_mfma_f32_16x16x32_f16(afr[0][3], bf3, ac0, 0,0,0);  \
    ac1 = __builtin_amdgcn_mfma_f32_16x16x32_f16(afr[1][3], bf3, ac1, 0,0,0);  \
    ac2 = __builtin_amdgcn_mfma_f32_16x16x32_f16(afr[2][3], bf3, ac2, 0,0,0);  \
    bool active = (tstep) < len;                                               \
    f16x4 hq;                                                                  \
    _Pragma("unroll")                                                          \
    for (int i = 0; i < 4; ++i) {                                              \
      float rr = sigm(GV0[i] + ac0[i] + bh0[i]);                               \
      float zz = sigm(GV1[i] + ac1[i] + bh1[i]);                               \
      float nn = fast_tanh(fmaf(rr, ac2[i] + bh2[i], GV2[i]));                 \
      float hn = (1.0f - zz) * nn + zz * h_own[i];                             \
      hn = active ? hn : 0.0f;                                                 \
      h_own[i] = hn;                                                           \
      hq[i] = (_Float16)hn;                                                    \
    }                                                                          \
    if (active) *(f32x4*)(outp + (size_t)(tstep) * D2) = h_own;                \
    {                                                                          \
      _Float16* hbW = hb + ((PB) ^ 1) * 2048;                                  \
      *(f16x4*)(hbW + seq * 128 + (j0 ^ ((seq & 7) << 3))) = hq;               \
    }                                                                          \
    K4_PF(GV0, GV1, GV2, (tstep) + 4);                                         \
    K4_BAR();                                                                  \
  } while (0)

  // prologue: prefetch t=0..3 (len >= 256 always)
  f32x4 gA0, gA1, gA2, gB0, gB1, gB2, gC0, gC1, gC2, gD0, gD1, gD2;
  K4_PF(gA0, gA1, gA2, 0);
  K4_PF(gB0, gB1, gB2, 1);
  K4_PF(gC0, gC1, gC2, 2);
  K4_PF(gD0, gD1, gD2, 3);
  K4_BAR();   // hb parity-0 init visible; global prefetches stay in flight

  int t = 0;
  while (t + 3 < maxlen) {   // t multiple of 4 -> parities 0,1,0,1
    K4_STEP(gA0, gA1, gA2, t,     0);
    K4_STEP(gB0, gB1, gB2, t + 1, 1);
    K4_STEP(gC0, gC1, gC2, t + 2, 0);
    K4_STEP(gD0, gD1, gD2, t + 3, 1);
    t += 4;
  }
  if (t < maxlen)     K4_STEP(gA0, gA1, gA2, t,     0);
  if (t + 1 < maxlen) K4_STEP(gB0, gB1, gB2, t + 1, 1);
  if (t + 2 < maxlen) K4_STEP(gC0, gC1, gC2, t + 2, 0);

#undef K4_STEP
#undef K4_PF
#undef K4_BAR
}

extern "C" void kernel_launch(void* const* d_in, const int* in_sizes, int n_in,
                              void* d_out, int out_size, void* d_ws, size_t ws_size,
                              hipStream_t stream) {
  const float* vp   = (const float*)d_in[0];
  const int*   lens = (const int*)d_in[1];
  const float* Wvp  = (const float*)d_in[2];
  const float* Wvpt = (const float*)d_in[3];
  const float* wvt  = (const float*)d_in[4];
  const float* Wg   = (const float*)d_in[5];
  const float* Wih  = (const float*)d_in[6];
  const float* Whh  = (const float*)d_in[7];
  const float* bih  = (const float*)d_in[8];
  const float* bhh  = (const float*)d_in[9];
  float* out = (float*)d_out;
  float* ws  = (float*)d_ws;

  hipMemsetAsync(d_out, 0, (size_t)out_size * sizeof(float), stream);

  k0_prep<<<2048, 256, 0, stream>>>(Wg, Wih, Wvp, Wvpt, ws);
  k1_keyq<<<BB * SS / 64, 256, 0, stream>>>(vp, ws);
  k2_attn<<<1024, 256, 0, stream>>>(vp, lens, wvt, ws);
  k3_gates<<<dim3(SS / 32, BB), 256, 0, stream>>>(vp, lens, bih, ws);
  k4_scan<<<4, 512, 0, stream>>>(Whh, bhh, lens, ws, out);
}

// Round 11
// 546.801 us; speedup vs baseline: 1.4399x; 1.4384x over previous
//
#include <hip/hip_runtime.h>
#include <hip/hip_fp16.h>

#define BB 32
#define SS 512
#define HH 128
#define D2 256
#define D3 384
#define D4 512

// ws layout (float offsets)
#define OFF_TK  0                       // Ek = exp(2*keyp) TRANSPOSED [B][H][S] f32
#define OFF_TQ  (OFF_TK + BB*SS*HH)     // Eq = exp(2*q)    [B][S][H] f32
#define OFF_CT  (OFF_TQ + BB*SS*HH)     // context   [B][S][2H] f32
#define OFF_GI  (OFF_CT + BB*SS*D2)     // gi        [B][S][3H] f32
#define OFF_F16 (OFF_GI + BB*SS*D3)     // f16 weight region below (element offsets)
#define F16_WG  0                       // Wg  f16 [512][512] row-major (as given)
#define F16_WIH (F16_WG + D4*D4)        // Wih f16 [384][512]
#define F16_W2  (F16_WIH + D3*D4)       // [WvP;WvPt] f16 [256][256]

typedef _Float16 f16x8 __attribute__((ext_vector_type(8)));
typedef _Float16 f16x4 __attribute__((ext_vector_type(4)));
typedef float    f32x4 __attribute__((ext_vector_type(4)));
typedef _Float16 h2_t  __attribute__((ext_vector_type(2)));

__device__ __forceinline__ float fast_tanh(float x) {
  float ax = fabsf(x);
  float e  = __expf(-2.0f * ax);
  float t  = __fdividef(1.0f - e, 1.0f + e);
  return x < 0.0f ? -t : t;
}
__device__ __forceinline__ float sigm(float x) {
  return __fdividef(1.0f, 1.0f + __expf(-x));
}

// ---------------- K0: convert weights to f16 in ws ----------------
__global__ __launch_bounds__(256) void k0_prep(
    const float* __restrict__ Wg, const float* __restrict__ Wih,
    const float* __restrict__ Wvp, const float* __restrict__ Wvpt,
    float* __restrict__ ws) {
  int i = blockIdx.x * 256 + threadIdx.x;
  _Float16* f16b = (_Float16*)(ws + OFF_F16);
  if (i < D4 * D4) {
    f16b[F16_WG + i] = (_Float16)Wg[i];
  } else if (i < D4 * D4 + D3 * D4) {
    int j = i - D4 * D4;
    f16b[F16_WIH + j] = (_Float16)Wih[j];
  } else {
    int j = i - D4 * D4 - D3 * D4;   // < 65536
    f16b[F16_W2 + j] = (_Float16)(j < HH * D2 ? Wvp[j] : Wvpt[j - HH * D2]);
  }
}

// ---------------- K1: Ek^T / Eq = exp(2 * ([WvP;WvPt] . vp^T)) via MFMA ----------------
__global__ __launch_bounds__(256, 2) void k1_keyq(const float* __restrict__ vp,
                                                  float* __restrict__ ws) {
  __shared__ __align__(16) _Float16 vpH[64 * 256];
  int tid = threadIdx.x;
  int rows0 = blockIdx.x * 64;

  #pragma unroll
  for (int i = 0; i < 8; ++i) {
    int u = tid + i * 256;
    int r = u >> 5, c8 = u & 31;
    const float* src = vp + (size_t)(rows0 + r) * D2 + c8 * 8;
    float4 a = *(const float4*)src;
    float4 b = *(const float4*)(src + 4);
    f16x8 h;
    h[0]=(_Float16)a.x; h[1]=(_Float16)a.y; h[2]=(_Float16)a.z; h[3]=(_Float16)a.w;
    h[4]=(_Float16)b.x; h[5]=(_Float16)b.y; h[6]=(_Float16)b.z; h[7]=(_Float16)b.w;
    *(f16x8*)(&vpH[r * 256 + (c8 ^ (r & 7)) * 8]) = h;
  }
  __syncthreads();

  const _Float16* W2 = (const _Float16*)(ws + OFF_F16) + F16_W2;
  int w = tid >> 6, l = tid & 63;
  int lr = l & 15, lk = (l >> 4) * 8;

  f32x4 acc[4][4];
  #pragma unroll
  for (int m = 0; m < 4; ++m)
    #pragma unroll
    for (int n = 0; n < 4; ++n) acc[m][n] = (f32x4){0.f, 0.f, 0.f, 0.f};

  for (int kc = 0; kc < 8; ++kc) {
    int k = kc * 32 + lk;
    f16x8 bf[4];
    #pragma unroll
    for (int n = 0; n < 4; ++n) {
      int r = n * 16 + lr;
      bf[n] = *(const f16x8*)(&vpH[r * 256 + (((k >> 3) ^ (r & 7))) * 8]);
    }
    #pragma unroll
    for (int m = 0; m < 4; ++m) {
      int c = w * 64 + m * 16 + lr;
      f16x8 af = *(const f16x8*)(W2 + (size_t)c * 256 + k);
      #pragma unroll
      for (int n = 0; n < 4; ++n)
        acc[m][n] = __builtin_amdgcn_mfma_f32_16x16x32_f16(af, bf[n], acc[m][n], 0, 0, 0);
    }
  }

  int b = rows0 >> 9;          // batch
  int s0 = rows0 & 511;        // s offset within batch
  float* ekT = ws + OFF_TK + (size_t)b * HH * SS;
  float* eqp = ws + OFF_TQ + (size_t)b * SS * HH;
  #pragma unroll
  for (int m = 0; m < 4; ++m) {
    int c0 = w * 64 + m * 16 + (l >> 4) * 4;
    #pragma unroll
    for (int n = 0; n < 4; ++n) {
      int s = s0 + n * 16 + lr;
      float v[4];
      #pragma unroll
      for (int j = 0; j < 4; ++j) {
        float z = fminf(fmaxf(2.0f * acc[m][n][j], -60.0f), 60.0f);
        v[j] = __expf(z);
      }
      if (c0 < HH) {
        // Ek transposed: [h][s]
        #pragma unroll
        for (int j = 0; j < 4; ++j)
          ekT[(size_t)(c0 + j) * SS + s] = v[j];
      } else {
        float4 o; o.x = v[0]; o.y = v[1]; o.z = v[2]; o.w = v[3];
        *(float4*)(eqp + (size_t)s * HH + (c0 - HH)) = o;
      }
    }
  }
}

// ---------------- K2: logits via exp-form tanh + softmax + ct ----------------
// 1-D grid 1024 blocks: bid = [t:5][q:2][xcd:3]; all 32 t-tiles of batch b
// share one XCD. No Eqs LDS (q4 read as wave-uniform L2 loads) -> LDS 32.1KB
// -> 4 blocks/CU. Two s-columns merged in one pass (shared q4/w4).
__global__ __launch_bounds__(256) void k2_attn(const float* __restrict__ vp,
                                               const int* __restrict__ lens,
                                               const float* __restrict__ wvt,
                                               float* __restrict__ ws) {
  int bid = blockIdx.x;                 // 0..1023
  int b  = (bid & 7) * 4 + ((bid >> 3) & 3);
  int t0 = (bid >> 5) * 16;             // 0..496
  int len = lens[b];
  if (t0 >= len) return;
  int nt = min(16, len - t0);

  __shared__ float L[16][SS];           // 32KB
  __shared__ float inv_sum[16];

  int tid = threadIdx.x;
  const float* EkT = ws + OFF_TK + (size_t)b * HH * SS;
  const float* Eqb = ws + OFF_TQ + ((size_t)b * SS + t0) * HH;

  // logits: tanh(k+q) = 1 - 2/(Ek*Eq+1); softmax shift-invariance drops the
  // constant sum(w) term -> L = -2 * sum_h w_h * rcp(Ek*Eq+1).
  // Thread owns s-cols {tid, tid+256}; s0 < 256 <= len always valid.
  {
    int s0 = tid, s1 = tid + 256;
    float acc0[16] = {}, acc1[16] = {};
    for (int h4 = 0; h4 < 32; ++h4) {
      const float* ek = EkT + (size_t)(h4 * 4) * SS;
      float ka0 = ek[s0],          kb0 = ek[s1];
      float ka1 = ek[SS + s0],     kb1 = ek[SS + s1];
      float ka2 = ek[2 * SS + s0], kb2 = ek[2 * SS + s1];
      float ka3 = ek[3 * SS + s0], kb3 = ek[3 * SS + s1];
      const float4 w4 = *(const float4*)(wvt + h4 * 4);
      #pragma unroll
      for (int t = 0; t < 16; ++t) {
        const float4 q4 = *(const float4*)(Eqb + (size_t)t * HH + h4 * 4);
        float r0 = __builtin_amdgcn_rcpf(fmaf(ka0, q4.x, 1.0f));
        float r1 = __builtin_amdgcn_rcpf(fmaf(ka1, q4.y, 1.0f));
        float r2 = __builtin_amdgcn_rcpf(fmaf(ka2, q4.z, 1.0f));
        float r3 = __builtin_amdgcn_rcpf(fmaf(ka3, q4.w, 1.0f));
        float u0 = __builtin_amdgcn_rcpf(fmaf(kb0, q4.x, 1.0f));
        float u1 = __builtin_amdgcn_rcpf(fmaf(kb1, q4.y, 1.0f));
        float u2 = __builtin_amdgcn_rcpf(fmaf(kb2, q4.z, 1.0f));
        float u3 = __builtin_amdgcn_rcpf(fmaf(kb3, q4.w, 1.0f));
        float a = acc0[t];
        a = fmaf(w4.x, r0, a);
        a = fmaf(w4.y, r1, a);
        a = fmaf(w4.z, r2, a);
        a = fmaf(w4.w, r3, a);
        acc0[t] = a;
        float c = acc1[t];
        c = fmaf(w4.x, u0, c);
        c = fmaf(w4.y, u1, c);
        c = fmaf(w4.z, u2, c);
        c = fmaf(w4.w, u3, c);
        acc1[t] = c;
      }
    }
    #pragma unroll
    for (int t = 0; t < 16; ++t) {
      L[t][s0] = -2.0f * acc0[t];
      L[t][s1] = -2.0f * acc1[t];
    }
  }
  __syncthreads();

  // softmax (store unnormalized exp; denominators in inv_sum)
  {
    int w = tid >> 6, lane = tid & 63;
    for (int ii = 0; ii < 4; ++ii) {
      int i = w + ii * 4;
      if (i < nt) {
        float m = -1e30f;
        for (int s = lane; s < len; s += 64) m = fmaxf(m, L[i][s]);
        #pragma unroll
        for (int off = 32; off > 0; off >>= 1) m = fmaxf(m, __shfl_xor(m, off));
        float sm = 0.0f;
        for (int s = lane; s < len; s += 64) {
          float e = __expf(L[i][s] - m);
          L[i][s] = e;
          sm += e;
        }
        #pragma unroll
        for (int off = 32; off > 0; off >>= 1) sm += __shfl_xor(sm, off);
        if (lane == 0) inv_sum[i] = __fdividef(1.0f, sm);
      }
    }
  }
  __syncthreads();

  // ct[t][d] = sum_s p[t][s] * vp[b][s][d]   (vp direct from L1/L2; p reads
  // are wave-uniform LDS broadcasts)
  int d4 = (tid & 63) * 4;
  int tg = tid >> 6;
  float4 acc4[4] = {};
  const float* vpb = vp + (size_t)b * SS * D2;
  int s = 0;
  for (; s + 4 <= len; s += 4) {
    #pragma unroll
    for (int u = 0; u < 4; ++u) {
      float4 v4 = *(const float4*)(vpb + (size_t)(s + u) * D2 + d4);
      #pragma unroll
      for (int j = 0; j < 4; ++j) {
        float p = L[tg * 4 + j][s + u];
        acc4[j].x = fmaf(p, v4.x, acc4[j].x);
        acc4[j].y = fmaf(p, v4.y, acc4[j].y);
        acc4[j].z = fmaf(p, v4.z, acc4[j].z);
        acc4[j].w = fmaf(p, v4.w, acc4[j].w);
      }
    }
  }
  for (; s < len; ++s) {
    float4 v4 = *(const float4*)(vpb + (size_t)s * D2 + d4);
    #pragma unroll
    for (int j = 0; j < 4; ++j) {
      float p = L[tg * 4 + j][s];
      acc4[j].x = fmaf(p, v4.x, acc4[j].x);
      acc4[j].y = fmaf(p, v4.y, acc4[j].y);
      acc4[j].z = fmaf(p, v4.z, acc4[j].z);
      acc4[j].w = fmaf(p, v4.w, acc4[j].w);
    }
  }
  float* ctg = ws + OFF_CT + ((size_t)b * SS + t0) * D2;
  #pragma unroll
  for (int j = 0; j < 4; ++j) {
    int t = tg * 4 + j;
    if (t < nt) {
      float is = inv_sum[t];
      float4 o;
      o.x = acc4[j].x * is; o.y = acc4[j].y * is;
      o.z = acc4[j].z * is; o.w = acc4[j].w * is;
      *(float4*)(ctg + (size_t)t * D2 + d4) = o;
    }
  }
}

// ---------------- K3: gt' = Wg.vpc^T -> xin (in-place LDS) -> gi' = Wih.xin^T ----------------
__global__ __launch_bounds__(256, 2) void k3_gates(const float* __restrict__ vp,
                                                   const int* __restrict__ lens,
                                                   const float* __restrict__ bih,
                                                   float* __restrict__ ws) {
  int b = blockIdx.y;
  int len = lens[b];
  int t0 = blockIdx.x * 32;
  if (t0 >= len) return;

  __shared__ __align__(16) _Float16 vpcH[32 * 512];
  int tid = threadIdx.x;
  const float* ct = ws + OFF_CT;

  #pragma unroll
  for (int i = 0; i < 8; ++i) {
    int u = tid + i * 256;
    int r = u >> 6, c8 = u & 63;
    int c = c8 * 8;
    const float* src = (c < D2) ? (vp + ((size_t)b * SS + t0 + r) * D2 + c)
                                : (ct + ((size_t)b * SS + t0 + r) * D2 + (c - D2));
    float4 a = *(const float4*)src;
    float4 bb = *(const float4*)(src + 4);
    f16x8 h;
    h[0]=(_Float16)a.x;  h[1]=(_Float16)a.y;  h[2]=(_Float16)a.z;  h[3]=(_Float16)a.w;
    h[4]=(_Float16)bb.x; h[5]=(_Float16)bb.y; h[6]=(_Float16)bb.z; h[7]=(_Float16)bb.w;
    *(f16x8*)(&vpcH[r * 512 + (c8 ^ (r & 7)) * 8]) = h;
  }
  __syncthreads();

  const _Float16* WgH  = (const _Float16*)(ws + OFF_F16) + F16_WG;
  const _Float16* WihH = (const _Float16*)(ws + OFF_F16) + F16_WIH;
  int w = tid >> 6, l = tid & 63;
  int lr = l & 15, lk = (l >> 4) * 8;

  f32x4 acc[8][2];
  #pragma unroll
  for (int m = 0; m < 8; ++m) { acc[m][0] = (f32x4){0.f,0.f,0.f,0.f}; acc[m][1] = (f32x4){0.f,0.f,0.f,0.f}; }

  for (int kc = 0; kc < 16; ++kc) {
    int k = kc * 32 + lk;
    f16x8 bf[2];
    #pragma unroll
    for (int n = 0; n < 2; ++n) {
      int r = n * 16 + lr;
      bf[n] = *(const f16x8*)(&vpcH[r * 512 + (((k >> 3) ^ (r & 7))) * 8]);
    }
    #pragma unroll
    for (int m = 0; m < 8; ++m) {
      int c = w * 128 + m * 16 + lr;
      f16x8 af = *(const f16x8*)(WgH + (size_t)c * 512 + k);
      acc[m][0] = __builtin_amdgcn_mfma_f32_16x16x32_f16(af, bf[0], acc[m][0], 0, 0, 0);
      acc[m][1] = __builtin_amdgcn_mfma_f32_16x16x32_f16(af, bf[1], acc[m][1], 0, 0, 0);
    }
  }

  f16x4 xq[8][2];
  #pragma unroll
  for (int m = 0; m < 8; ++m) {
    int c0 = w * 128 + m * 16 + (l >> 4) * 4;
    #pragma unroll
    for (int n = 0; n < 2; ++n) {
      int r = n * 16 + lr;
      int ea = r * 512 + (((c0 >> 3) ^ (r & 7))) * 8 + (c0 & 7);
      f16x4 vq = *(const f16x4*)(&vpcH[ea]);
      f16x4 xo;
      #pragma unroll
      for (int j = 0; j < 4; ++j)
        xo[j] = (_Float16)(sigm(acc[m][n][j]) * (float)vq[j]);
      xq[m][n] = xo;
    }
  }
  __syncthreads();
  #pragma unroll
  for (int m = 0; m < 8; ++m) {
    int c0 = w * 128 + m * 16 + (l >> 4) * 4;
    #pragma unroll
    for (int n = 0; n < 2; ++n) {
      int r = n * 16 + lr;
      int ea = r * 512 + (((c0 >> 3) ^ (r & 7))) * 8 + (c0 & 7);
      *(f16x4*)(&vpcH[ea]) = xq[m][n];
    }
  }
  __syncthreads();

  f32x4 gacc[6][2];
  #pragma unroll
  for (int m = 0; m < 6; ++m) { gacc[m][0] = (f32x4){0.f,0.f,0.f,0.f}; gacc[m][1] = (f32x4){0.f,0.f,0.f,0.f}; }

  for (int kc = 0; kc < 16; ++kc) {
    int k = kc * 32 + lk;
    f16x8 bf[2];
    #pragma unroll
    for (int n = 0; n < 2; ++n) {
      int r = n * 16 + lr;
      bf[n] = *(const f16x8*)(&vpcH[r * 512 + (((k >> 3) ^ (r & 7))) * 8]);
    }
    #pragma unroll
    for (int m = 0; m < 6; ++m) {
      int c = w * 96 + m * 16 + lr;
      f16x8 af = *(const f16x8*)(WihH + (size_t)c * 512 + k);
      gacc[m][0] = __builtin_amdgcn_mfma_f32_16x16x32_f16(af, bf[0], gacc[m][0], 0, 0, 0);
      gacc[m][1] = __builtin_amdgcn_mfma_f32_16x16x32_f16(af, bf[1], gacc[m][1], 0, 0, 0);
    }
  }

  float* gig = ws + OFF_GI;
  #pragma unroll
  for (int m = 0; m < 6; ++m) {
    int c0 = w * 96 + m * 16 + (l >> 4) * 4;
    float4 bq = *(const float4*)(bih + c0);
    #pragma unroll
    for (int n = 0; n < 2; ++n) {
      int r = n * 16 + lr;
      float4 o;
      o.x = gacc[m][n][0] + bq.x;
      o.y = gacc[m][n][1] + bq.y;
      o.z = gacc[m][n][2] + bq.z;
      o.w = gacc[m][n][3] + bq.w;
      *(float4*)(gig + ((size_t)b * SS + t0 + r) * D3 + c0) = o;
    }
  }
}

// ---------------- K4: GRU scan (R7 config: best measured, 279us).
// 256 threads, pair-split K (lane l: unit j = 32*wave + (l&31), K-half
// p = l>>5). 96 weight VGPRs/thread (no spill), shfl_xor(32) combine
// (no gsum LDS), double-buffered hbuf, ONE barrier/step, depth-4 gi
// prefetch that stays in flight across barriers. ----------------
__global__ __launch_bounds__(256, 1) void k4_scan(const float* __restrict__ whh,
                                                  const float* __restrict__ bhh,
                                                  const int* __restrict__ lens,
                                                  const float* __restrict__ ws,
                                                  float* __restrict__ out) {
  int bid = blockIdx.x;
  // XCD-pair swizzle: fwd/rev of same b land on the same XCD (bid%8 preserved)
  int xcd = bid & 7, dir = (bid >> 3) & 1, q = bid >> 4;
  int b = xcd * 4 + q;
  int len = lens[b];
  int tid = threadIdx.x;            // 0..255
  int wv = tid >> 6, l = tid & 63;
  int j = wv * 32 + (l & 31);       // hidden unit 0..127
  int p = l >> 5;                   // K-half 0/1
  const float* gi = ws + OFF_GI + (size_t)b * SS * D3;

  // register-resident: 3 W_hh rows (r,z,n for unit j), K range [p*64, p*64+64)
  h2_t w0[32], w1[32], w2[32];
  {
    const float* r0 = whh + (size_t)j * HH + p * 64;
    const float* r1 = whh + (size_t)(j + 128) * HH + p * 64;
    const float* r2 = whh + (size_t)(j + 256) * HH + p * 64;
    #pragma unroll
    for (int k = 0; k < 32; ++k) {
      w0[k] = h2_t{(_Float16)r0[2 * k], (_Float16)r0[2 * k + 1]};
      w1[k] = h2_t{(_Float16)r1[2 * k], (_Float16)r1[2 * k + 1]};
      w2[k] = h2_t{(_Float16)r2[2 * k], (_Float16)r2[2 * k + 1]};
    }
  }
  float bh0 = bhh[j], bh1 = bhh[j + 128], bh2 = bhh[j + 256];

  __shared__ __align__(16) _Float16 hbuf[2][128];
  if (tid < 128) hbuf[0][tid] = (_Float16)0.0f;
  float h_own = 0.0f;

  float* outb = out + (size_t)b * SS * D2 + dir * HH;

#define K4_BAR() do {                                                          \
    asm volatile("s_waitcnt lgkmcnt(0)" ::: "memory");                         \
    __builtin_amdgcn_s_barrier();                                              \
    __builtin_amdgcn_sched_barrier(0);                                         \
  } while (0)

#define K4_PF(gx0, gx1, gx2, tnext) do {                                       \
    if (p == 0) {                                                              \
      int tp = (tnext) < len ? (tnext) : (len - 1);                            \
      int tgp = dir ? (len - 1 - tp) : tp;                                     \
      const float* gp = gi + (size_t)tgp * D3;                                 \
      gx0 = gp[j]; gx1 = gp[j + 128]; gx2 = gp[j + 256];                       \
    }                                                                          \
  } while (0)

  // one step: read h-half from hbuf[PB], 96 fdot2, shfl_xor(32) combine,
  // gates in p=0 lanes, write hbuf[PB^1] + out, prefetch t+4, one barrier.
#define K4_STEP(gx0, gx1, gx2, tstep, PB) do {                                 \
    const f16x8* hb8 = (const f16x8*)&hbuf[PB][p * 64];                        \
    float a00 = 0.f, a01 = 0.f, a02 = 0.f, a03 = 0.f;                          \
    float a10 = 0.f, a11 = 0.f, a12 = 0.f, a13 = 0.f;                          \
    float a20 = 0.f, a21 = 0.f, a22 = 0.f, a23 = 0.f;                          \
    _Pragma("unroll")                                                          \
    for (int k8 = 0; k8 < 8; ++k8) {                                           \
      f16x8 hv = hb8[k8];                                                      \
      h2_t q0 = __builtin_shufflevector(hv, hv, 0, 1);                         \
      h2_t q1 = __builtin_shufflevector(hv, hv, 2, 3);                         \
      h2_t q2 = __builtin_shufflevector(hv, hv, 4, 5);                         \
      h2_t q3 = __builtin_shufflevector(hv, hv, 6, 7);                         \
      a00 = __builtin_amdgcn_fdot2(q0, w0[4 * k8 + 0], a00, false);            \
      a01 = __builtin_amdgcn_fdot2(q1, w0[4 * k8 + 1], a01, false);            \
      a02 = __builtin_amdgcn_fdot2(q2, w0[4 * k8 + 2], a02, false);            \
      a03 = __builtin_amdgcn_fdot2(q3, w0[4 * k8 + 3], a03, false);            \
      a10 = __builtin_amdgcn_fdot2(q0, w1[4 * k8 + 0], a10, false);            \
      a11 = __builtin_amdgcn_fdot2(q1, w1[4 * k8 + 1], a11, false);            \
      a12 = __builtin_amdgcn_fdot2(q2, w1[4 * k8 + 2], a12, false);            \
      a13 = __builtin_amdgcn_fdot2(q3, w1[4 * k8 + 3], a13, false);            \
      a20 = __builtin_amdgcn_fdot2(q0, w2[4 * k8 + 0], a20, false);            \
      a21 = __builtin_amdgcn_fdot2(q1, w2[4 * k8 + 1], a21, false);            \
      a22 = __builtin_amdgcn_fdot2(q2, w2[4 * k8 + 2], a22, false);            \
      a23 = __builtin_amdgcn_fdot2(q3, w2[4 * k8 + 3], a23, false);            \
    }                                                                          \
    float s0 = ((a00 + a01) + (a02 + a03));                                    \
    float s1 = ((a10 + a11) + (a12 + a13));                                    \
    float s2 = ((a20 + a21) + (a22 + a23));                                    \
    s0 += __shfl_xor(s0, 32);                                                  \
    s1 += __shfl_xor(s1, 32);                                                  \
    s2 += __shfl_xor(s2, 32);                                                  \
    if (p == 0) {                                                              \
      float r = sigm((gx0) + s0 + bh0);                                        \
      float z = sigm((gx1) + s1 + bh1);                                        \
      float n = fast_tanh(fmaf(r, s2 + bh2, (gx2)));                           \
      float hn = (1.0f - z) * n + z * h_own;                                   \
      h_own = hn;                                                              \
      outb[(size_t)(tstep) * D2 + j] = hn;                                     \
      hbuf[(PB) ^ 1][j] = (_Float16)hn;                                        \
    }                                                                          \
    K4_PF(gx0, gx1, gx2, (tstep) + 4);                                         \
    K4_BAR();                                                                  \
  } while (0)

  // prologue: prefetch t=0..3 (len >= 256 always)
  float gA0 = 0.f, gA1 = 0.f, gA2 = 0.f;
  float gB0 = 0.f, gB1 = 0.f, gB2 = 0.f;
  float gC0 = 0.f, gC1 = 0.f, gC2 = 0.f;
  float gD0 = 0.f, gD1 = 0.f, gD2 = 0.f;
  K4_PF(gA0, gA1, gA2, 0);
  K4_PF(gB0, gB1, gB2, 1);
  K4_PF(gC0, gC1, gC2, 2);
  K4_PF(gD0, gD1, gD2, 3);
  K4_BAR();   // hbuf[0] init visible; global prefetches stay in flight

  int t = 0;
  while (t + 3 < len) {      // t stays a multiple of 4 -> parities 0,1,0,1
    K4_STEP(gA0, gA1, gA2, t,     0);
    K4_STEP(gB0, gB1, gB2, t + 1, 1);
    K4_STEP(gC0, gC1, gC2, t + 2, 0);
    K4_STEP(gD0, gD1, gD2, t + 3, 1);
    t += 4;
  }
  if (t < len)     K4_STEP(gA0, gA1, gA2, t,     0);
  if (t + 1 < len) K4_STEP(gB0, gB1, gB2, t + 1, 1);
  if (t + 2 < len) K4_STEP(gC0, gC1, gC2, t + 2, 0);

#undef K4_STEP
#undef K4_PF
#undef K4_BAR
}

extern "C" void kernel_launch(void* const* d_in, const int* in_sizes, int n_in,
                              void* d_out, int out_size, void* d_ws, size_t ws_size,
                              hipStream_t stream) {
  const float* vp   = (const float*)d_in[0];
  const int*   lens = (const int*)d_in[1];
  const float* Wvp  = (const float*)d_in[2];
  const float* Wvpt = (const float*)d_in[3];
  const float* wvt  = (const float*)d_in[4];
  const float* Wg   = (const float*)d_in[5];
  const float* Wih  = (const float*)d_in[6];
  const float* Whh  = (const float*)d_in[7];
  const float* bih  = (const float*)d_in[8];
  const float* bhh  = (const float*)d_in[9];
  float* out = (float*)d_out;
  float* ws  = (float*)d_ws;

  hipMemsetAsync(d_out, 0, (size_t)out_size * sizeof(float), stream);

  k0_prep<<<2048, 256, 0, stream>>>(Wg, Wih, Wvp, Wvpt, ws);
  k1_keyq<<<BB * SS / 64, 256, 0, stream>>>(vp, ws);
  k2_attn<<<1024, 256, 0, stream>>>(vp, lens, wvt, ws);
  k3_gates<<<dim3(SS / 32, BB), 256, 0, stream>>>(vp, lens, bih, ws);
  k4_scan<<<64, 256, 0, stream>>>(Whh, bhh, lens, ws, out);
}

// Round 12
// 531.994 us; speedup vs baseline: 1.4800x; 1.0278x over previous
//
#include <hip/hip_runtime.h>
#include <hip/hip_fp16.h>

#define BB 32
#define SS 512
#define HH 128
#define D2 256
#define D3 384
#define D4 512

// ws layout (float offsets)
#define OFF_TK  0                       // Ek = exp(2*keyp) TRANSPOSED [B][H][S] f32
#define OFF_TQ  (OFF_TK + BB*SS*HH)     // Eq = exp(2*q)    [B][S][H] f32
#define OFF_CT  (OFF_TQ + BB*SS*HH)     // context   [B][S][2H] f32
#define OFF_GI  (OFF_CT + BB*SS*D2)     // gi        [B][S][3H] f32
#define OFF_F16 (OFF_GI + BB*SS*D3)     // f16 weight region below (element offsets)
#define F16_WG  0                       // Wg  f16 [512][512] row-major (as given)
#define F16_WIH (F16_WG + D4*D4)        // Wih f16 [384][512]
#define F16_W2  (F16_WIH + D3*D4)       // [WvP;WvPt] f16 [256][256]

typedef _Float16 f16x8 __attribute__((ext_vector_type(8)));
typedef _Float16 f16x4 __attribute__((ext_vector_type(4)));
typedef float    f32x4 __attribute__((ext_vector_type(4)));
typedef _Float16 h2_t  __attribute__((ext_vector_type(2)));

__device__ __forceinline__ float fast_tanh(float x) {
  float ax = fabsf(x);
  float e  = __expf(-2.0f * ax);
  float t  = __fdividef(1.0f - e, 1.0f + e);
  return x < 0.0f ? -t : t;
}
__device__ __forceinline__ float sigm(float x) {
  return __fdividef(1.0f, 1.0f + __expf(-x));
}

// ---------------- K0: convert weights to f16 in ws ----------------
__global__ __launch_bounds__(256) void k0_prep(
    const float* __restrict__ Wg, const float* __restrict__ Wih,
    const float* __restrict__ Wvp, const float* __restrict__ Wvpt,
    float* __restrict__ ws) {
  int i = blockIdx.x * 256 + threadIdx.x;
  _Float16* f16b = (_Float16*)(ws + OFF_F16);
  if (i < D4 * D4) {
    f16b[F16_WG + i] = (_Float16)Wg[i];
  } else if (i < D4 * D4 + D3 * D4) {
    int j = i - D4 * D4;
    f16b[F16_WIH + j] = (_Float16)Wih[j];
  } else {
    int j = i - D4 * D4 - D3 * D4;   // < 65536
    f16b[F16_W2 + j] = (_Float16)(j < HH * D2 ? Wvp[j] : Wvpt[j - HH * D2]);
  }
}

// ---------------- K1: Ek^T / Eq = exp(2 * ([WvP;WvPt] . vp^T)) via MFMA ----------------
__global__ __launch_bounds__(256, 2) void k1_keyq(const float* __restrict__ vp,
                                                  float* __restrict__ ws) {
  __shared__ __align__(16) _Float16 vpH[64 * 256];
  int tid = threadIdx.x;
  int rows0 = blockIdx.x * 64;

  #pragma unroll
  for (int i = 0; i < 8; ++i) {
    int u = tid + i * 256;
    int r = u >> 5, c8 = u & 31;
    const float* src = vp + (size_t)(rows0 + r) * D2 + c8 * 8;
    float4 a = *(const float4*)src;
    float4 b = *(const float4*)(src + 4);
    f16x8 h;
    h[0]=(_Float16)a.x; h[1]=(_Float16)a.y; h[2]=(_Float16)a.z; h[3]=(_Float16)a.w;
    h[4]=(_Float16)b.x; h[5]=(_Float16)b.y; h[6]=(_Float16)b.z; h[7]=(_Float16)b.w;
    *(f16x8*)(&vpH[r * 256 + (c8 ^ (r & 7)) * 8]) = h;
  }
  __syncthreads();

  const _Float16* W2 = (const _Float16*)(ws + OFF_F16) + F16_W2;
  int w = tid >> 6, l = tid & 63;
  int lr = l & 15, lk = (l >> 4) * 8;

  f32x4 acc[4][4];
  #pragma unroll
  for (int m = 0; m < 4; ++m)
    #pragma unroll
    for (int n = 0; n < 4; ++n) acc[m][n] = (f32x4){0.f, 0.f, 0.f, 0.f};

  for (int kc = 0; kc < 8; ++kc) {
    int k = kc * 32 + lk;
    f16x8 bf[4];
    #pragma unroll
    for (int n = 0; n < 4; ++n) {
      int r = n * 16 + lr;
      bf[n] = *(const f16x8*)(&vpH[r * 256 + (((k >> 3) ^ (r & 7))) * 8]);
    }
    #pragma unroll
    for (int m = 0; m < 4; ++m) {
      int c = w * 64 + m * 16 + lr;
      f16x8 af = *(const f16x8*)(W2 + (size_t)c * 256 + k);
      #pragma unroll
      for (int n = 0; n < 4; ++n)
        acc[m][n] = __builtin_amdgcn_mfma_f32_16x16x32_f16(af, bf[n], acc[m][n], 0, 0, 0);
    }
  }

  int b = rows0 >> 9;          // batch
  int s0 = rows0 & 511;        // s offset within batch
  float* ekT = ws + OFF_TK + (size_t)b * HH * SS;
  float* eqp = ws + OFF_TQ + (size_t)b * SS * HH;
  #pragma unroll
  for (int m = 0; m < 4; ++m) {
    int c0 = w * 64 + m * 16 + (l >> 4) * 4;
    #pragma unroll
    for (int n = 0; n < 4; ++n) {
      int s = s0 + n * 16 + lr;
      float v[4];
      #pragma unroll
      for (int j = 0; j < 4; ++j) {
        float z = fminf(fmaxf(2.0f * acc[m][n][j], -60.0f), 60.0f);
        v[j] = __expf(z);
      }
      if (c0 < HH) {
        // Ek transposed: [h][s]
        #pragma unroll
        for (int j = 0; j < 4; ++j)
          ekT[(size_t)(c0 + j) * SS + s] = v[j];
      } else {
        float4 o; o.x = v[0]; o.y = v[1]; o.z = v[2]; o.w = v[3];
        *(float4*)(eqp + (size_t)s * HH + (c0 - HH)) = o;
      }
    }
  }
}

// ---------------- K2: logits via exp-form tanh + softmax + ct ----------------
// 1-D grid 1024 blocks: bid = [t:5][q:2][xcd:3]; all 32 t-tiles of batch b
// share one XCD. L stored as f16 t-pairs (16KB) + Eqs f32 (8KB) -> 24.4KB LDS
// -> 6 blocks/CU. Merged dual-s-column logits pass; q4 from LDS broadcast.
__global__ __launch_bounds__(256) void k2_attn(const float* __restrict__ vp,
                                               const int* __restrict__ lens,
                                               const float* __restrict__ wvt,
                                               float* __restrict__ ws) {
  int bid = blockIdx.x;                 // 0..1023
  int b  = (bid & 7) * 4 + ((bid >> 3) & 3);
  int t0 = (bid >> 5) * 16;             // 0..496
  int len = lens[b];
  if (t0 >= len) return;
  int nt = min(16, len - t0);

  __shared__ __align__(16) _Float16 Lh[8][SS][2];  // [t/2][s][t&1], 16KB
  __shared__ __align__(16) float Eqs[16][HH];      // 8KB
  __shared__ float inv_sum[16];

  int tid = threadIdx.x;
  const float* EkT = ws + OFF_TK + (size_t)b * HH * SS;
  const float* Eqg = ws + OFF_TQ + ((size_t)b * SS + t0) * HH;

  // stage Eq tile (16 x 128 f32) into LDS, vectorized
  for (int idx = tid; idx < 16 * HH / 4; idx += 256) {
    int i = idx >> 5, h4 = idx & 31;
    *(float4*)&Eqs[i][h4 * 4] = *(const float4*)(Eqg + (size_t)i * HH + h4 * 4);
  }
  __syncthreads();

  // logits: tanh(k+q) = 1 - 2/(Ek*Eq+1); softmax shift-invariance drops the
  // constant sum(w) term -> L = -2 * sum_h w_h * rcp(Ek*Eq+1).
  // Thread owns s-cols {tid, tid+256}; s0 < 256 <= len always valid.
  {
    int s0 = tid, s1 = tid + 256;
    float acc0[16] = {}, acc1[16] = {};
    for (int h4 = 0; h4 < 32; ++h4) {
      const float* ek = EkT + (size_t)(h4 * 4) * SS;
      float ka0 = ek[s0],          kb0 = ek[s1];
      float ka1 = ek[SS + s0],     kb1 = ek[SS + s1];
      float ka2 = ek[2 * SS + s0], kb2 = ek[2 * SS + s1];
      float ka3 = ek[3 * SS + s0], kb3 = ek[3 * SS + s1];
      const float4 w4 = *(const float4*)(wvt + h4 * 4);
      #pragma unroll
      for (int t = 0; t < 16; ++t) {
        const float4 q4 = *(const float4*)(&Eqs[t][h4 * 4]);
        float r0 = __builtin_amdgcn_rcpf(fmaf(ka0, q4.x, 1.0f));
        float r1 = __builtin_amdgcn_rcpf(fmaf(ka1, q4.y, 1.0f));
        float r2 = __builtin_amdgcn_rcpf(fmaf(ka2, q4.z, 1.0f));
        float r3 = __builtin_amdgcn_rcpf(fmaf(ka3, q4.w, 1.0f));
        float u0 = __builtin_amdgcn_rcpf(fmaf(kb0, q4.x, 1.0f));
        float u1 = __builtin_amdgcn_rcpf(fmaf(kb1, q4.y, 1.0f));
        float u2 = __builtin_amdgcn_rcpf(fmaf(kb2, q4.z, 1.0f));
        float u3 = __builtin_amdgcn_rcpf(fmaf(kb3, q4.w, 1.0f));
        float a = acc0[t];
        a = fmaf(w4.x, r0, a);
        a = fmaf(w4.y, r1, a);
        a = fmaf(w4.z, r2, a);
        a = fmaf(w4.w, r3, a);
        acc0[t] = a;
        float c = acc1[t];
        c = fmaf(w4.x, u0, c);
        c = fmaf(w4.y, u1, c);
        c = fmaf(w4.z, u2, c);
        c = fmaf(w4.w, u3, c);
        acc1[t] = c;
      }
    }
    #pragma unroll
    for (int tp = 0; tp < 8; ++tp) {
      h2_t v0, v1;
      v0[0] = (_Float16)(-2.0f * acc0[2 * tp]);
      v0[1] = (_Float16)(-2.0f * acc0[2 * tp + 1]);
      v1[0] = (_Float16)(-2.0f * acc1[2 * tp]);
      v1[1] = (_Float16)(-2.0f * acc1[2 * tp + 1]);
      *(h2_t*)&Lh[tp][s0][0] = v0;
      *(h2_t*)&Lh[tp][s1][0] = v1;
    }
  }
  __syncthreads();

  // softmax (store unnormalized exp as f16; denominators in inv_sum)
  {
    int w = tid >> 6, lane = tid & 63;
    for (int ii = 0; ii < 4; ++ii) {
      int i = w + ii * 4;
      if (i < nt) {
        int ip = i >> 1, il = i & 1;
        float m = -1e30f;
        for (int s = lane; s < len; s += 64) m = fmaxf(m, (float)Lh[ip][s][il]);
        #pragma unroll
        for (int off = 32; off > 0; off >>= 1) m = fmaxf(m, __shfl_xor(m, off));
        float sm = 0.0f;
        for (int s = lane; s < len; s += 64) {
          float e = __expf((float)Lh[ip][s][il] - m);
          Lh[ip][s][il] = (_Float16)e;
          sm += e;
        }
        #pragma unroll
        for (int off = 32; off > 0; off >>= 1) sm += __shfl_xor(sm, off);
        if (lane == 0) inv_sum[i] = __fdividef(1.0f, sm);
      }
    }
  }
  __syncthreads();

  // ct[t][d] = sum_s p[t][s] * vp[b][s][d]  (vp from L2; p reads are
  // wave-uniform f16x2 LDS broadcasts: 2 reads serve 4 t's)
  int d4 = (tid & 63) * 4;
  int tg = tid >> 6;
  float4 acc4[4] = {};
  const float* vpb = vp + (size_t)b * SS * D2;
  int s = 0;
  for (; s + 4 <= len; s += 4) {
    #pragma unroll
    for (int u = 0; u < 4; ++u) {
      float4 v4 = *(const float4*)(vpb + (size_t)(s + u) * D2 + d4);
      h2_t pA = *(const h2_t*)&Lh[tg * 2][s + u][0];      // t = 4tg, 4tg+1
      h2_t pB = *(const h2_t*)&Lh[tg * 2 + 1][s + u][0];  // t = 4tg+2, 4tg+3
      float p0 = (float)pA[0], p1 = (float)pA[1];
      float p2 = (float)pB[0], p3 = (float)pB[1];
      acc4[0].x = fmaf(p0, v4.x, acc4[0].x);
      acc4[0].y = fmaf(p0, v4.y, acc4[0].y);
      acc4[0].z = fmaf(p0, v4.z, acc4[0].z);
      acc4[0].w = fmaf(p0, v4.w, acc4[0].w);
      acc4[1].x = fmaf(p1, v4.x, acc4[1].x);
      acc4[1].y = fmaf(p1, v4.y, acc4[1].y);
      acc4[1].z = fmaf(p1, v4.z, acc4[1].z);
      acc4[1].w = fmaf(p1, v4.w, acc4[1].w);
      acc4[2].x = fmaf(p2, v4.x, acc4[2].x);
      acc4[2].y = fmaf(p2, v4.y, acc4[2].y);
      acc4[2].z = fmaf(p2, v4.z, acc4[2].z);
      acc4[2].w = fmaf(p2, v4.w, acc4[2].w);
      acc4[3].x = fmaf(p3, v4.x, acc4[3].x);
      acc4[3].y = fmaf(p3, v4.y, acc4[3].y);
      acc4[3].z = fmaf(p3, v4.z, acc4[3].z);
      acc4[3].w = fmaf(p3, v4.w, acc4[3].w);
    }
  }
  for (; s < len; ++s) {
    float4 v4 = *(const float4*)(vpb + (size_t)s * D2 + d4);
    h2_t pA = *(const h2_t*)&Lh[tg * 2][s][0];
    h2_t pB = *(const h2_t*)&Lh[tg * 2 + 1][s][0];
    float pj[4] = {(float)pA[0], (float)pA[1], (float)pB[0], (float)pB[1]};
    #pragma unroll
    for (int j = 0; j < 4; ++j) {
      acc4[j].x = fmaf(pj[j], v4.x, acc4[j].x);
      acc4[j].y = fmaf(pj[j], v4.y, acc4[j].y);
      acc4[j].z = fmaf(pj[j], v4.z, acc4[j].z);
      acc4[j].w = fmaf(pj[j], v4.w, acc4[j].w);
    }
  }
  float* ctg = ws + OFF_CT + ((size_t)b * SS + t0) * D2;
  #pragma unroll
  for (int j = 0; j < 4; ++j) {
    int t = tg * 4 + j;
    if (t < nt) {
      float is = inv_sum[t];
      float4 o;
      o.x = acc4[j].x * is; o.y = acc4[j].y * is;
      o.z = acc4[j].z * is; o.w = acc4[j].w * is;
      *(float4*)(ctg + (size_t)t * D2 + d4) = o;
    }
  }
}

// ---------------- K3: gt' = Wg.vpc^T -> xin (in-place LDS) -> gi' = Wih.xin^T ----------------
__global__ __launch_bounds__(256, 2) void k3_gates(const float* __restrict__ vp,
                                                   const int* __restrict__ lens,
                                                   const float* __restrict__ bih,
                                                   float* __restrict__ ws) {
  int b = blockIdx.y;
  int len = lens[b];
  int t0 = blockIdx.x * 32;
  if (t0 >= len) return;

  __shared__ __align__(16) _Float16 vpcH[32 * 512];
  int tid = threadIdx.x;
  const float* ct = ws + OFF_CT;

  #pragma unroll
  for (int i = 0; i < 8; ++i) {
    int u = tid + i * 256;
    int r = u >> 6, c8 = u & 63;
    int c = c8 * 8;
    const float* src = (c < D2) ? (vp + ((size_t)b * SS + t0 + r) * D2 + c)
                                : (ct + ((size_t)b * SS + t0 + r) * D2 + (c - D2));
    float4 a = *(const float4*)src;
    float4 bb = *(const float4*)(src + 4);
    f16x8 h;
    h[0]=(_Float16)a.x;  h[1]=(_Float16)a.y;  h[2]=(_Float16)a.z;  h[3]=(_Float16)a.w;
    h[4]=(_Float16)bb.x; h[5]=(_Float16)bb.y; h[6]=(_Float16)bb.z; h[7]=(_Float16)bb.w;
    *(f16x8*)(&vpcH[r * 512 + (c8 ^ (r & 7)) * 8]) = h;
  }
  __syncthreads();

  const _Float16* WgH  = (const _Float16*)(ws + OFF_F16) + F16_WG;
  const _Float16* WihH = (const _Float16*)(ws + OFF_F16) + F16_WIH;
  int w = tid >> 6, l = tid & 63;
  int lr = l & 15, lk = (l >> 4) * 8;

  f32x4 acc[8][2];
  #pragma unroll
  for (int m = 0; m < 8; ++m) { acc[m][0] = (f32x4){0.f,0.f,0.f,0.f}; acc[m][1] = (f32x4){0.f,0.f,0.f,0.f}; }

  for (int kc = 0; kc < 16; ++kc) {
    int k = kc * 32 + lk;
    f16x8 bf[2];
    #pragma unroll
    for (int n = 0; n < 2; ++n) {
      int r = n * 16 + lr;
      bf[n] = *(const f16x8*)(&vpcH[r * 512 + (((k >> 3) ^ (r & 7))) * 8]);
    }
    #pragma unroll
    for (int m = 0; m < 8; ++m) {
      int c = w * 128 + m * 16 + lr;
      f16x8 af = *(const f16x8*)(WgH + (size_t)c * 512 + k);
      acc[m][0] = __builtin_amdgcn_mfma_f32_16x16x32_f16(af, bf[0], acc[m][0], 0, 0, 0);
      acc[m][1] = __builtin_amdgcn_mfma_f32_16x16x32_f16(af, bf[1], acc[m][1], 0, 0, 0);
    }
  }

  f16x4 xq[8][2];
  #pragma unroll
  for (int m = 0; m < 8; ++m) {
    int c0 = w * 128 + m * 16 + (l >> 4) * 4;
    #pragma unroll
    for (int n = 0; n < 2; ++n) {
      int r = n * 16 + lr;
      int ea = r * 512 + (((c0 >> 3) ^ (r & 7))) * 8 + (c0 & 7);
      f16x4 vq = *(const f16x4*)(&vpcH[ea]);
      f16x4 xo;
      #pragma unroll
      for (int j = 0; j < 4; ++j)
        xo[j] = (_Float16)(sigm(acc[m][n][j]) * (float)vq[j]);
      xq[m][n] = xo;
    }
  }
  __syncthreads();
  #pragma unroll
  for (int m = 0; m < 8; ++m) {
    int c0 = w * 128 + m * 16 + (l >> 4) * 4;
    #pragma unroll
    for (int n = 0; n < 2; ++n) {
      int r = n * 16 + lr;
      int ea = r * 512 + (((c0 >> 3) ^ (r & 7))) * 8 + (c0 & 7);
      *(f16x4*)(&vpcH[ea]) = xq[m][n];
    }
  }
  __syncthreads();

  f32x4 gacc[6][2];
  #pragma unroll
  for (int m = 0; m < 6; ++m) { gacc[m][0] = (f32x4){0.f,0.f,0.f,0.f}; gacc[m][1] = (f32x4){0.f,0.f,0.f,0.f}; }

  for (int kc = 0; kc < 16; ++kc) {
    int k = kc * 32 + lk;
    f16x8 bf[2];
    #pragma unroll
    for (int n = 0; n < 2; ++n) {
      int r = n * 16 + lr;
      bf[n] = *(const f16x8*)(&vpcH[r * 512 + (((k >> 3) ^ (r & 7))) * 8]);
    }
    #pragma unroll
    for (int m = 0; m < 6; ++m) {
      int c = w * 96 + m * 16 + lr;
      f16x8 af = *(const f16x8*)(WihH + (size_t)c * 512 + k);
      gacc[m][0] = __builtin_amdgcn_mfma_f32_16x16x32_f16(af, bf[0], gacc[m][0], 0, 0, 0);
      gacc[m][1] = __builtin_amdgcn_mfma_f32_16x16x32_f16(af, bf[1], gacc[m][1], 0, 0, 0);
    }
  }

  float* gig = ws + OFF_GI;
  #pragma unroll
  for (int m = 0; m < 6; ++m) {
    int c0 = w * 96 + m * 16 + (l >> 4) * 4;
    float4 bq = *(const float4*)(bih + c0);
    #pragma unroll
    for (int n = 0; n < 2; ++n) {
      int r = n * 16 + lr;
      float4 o;
      o.x = gacc[m][n][0] + bq.x;
      o.y = gacc[m][n][1] + bq.y;
      o.z = gacc[m][n][2] + bq.z;
      o.w = gacc[m][n][3] + bq.w;
      *(float4*)(gig + ((size_t)b * SS + t0 + r) * D3 + c0) = o;
    }
  }
}

// ---------------- K4: GRU scan (R7 config: best measured, 279us).
// 256 threads, pair-split K (lane l: unit j = 32*wave + (l&31), K-half
// p = l>>5). 96 weight VGPRs/thread (no spill), shfl_xor(32) combine
// (no gsum LDS), double-buffered hbuf, ONE barrier/step, depth-4 gi
// prefetch that stays in flight across barriers. ----------------
__global__ __launch_bounds__(256, 1) void k4_scan(const float* __restrict__ whh,
                                                  const float* __restrict__ bhh,
                                                  const int* __restrict__ lens,
                                                  const float* __restrict__ ws,
                                                  float* __restrict__ out) {
  int bid = blockIdx.x;
  // XCD-pair swizzle: fwd/rev of same b land on the same XCD (bid%8 preserved)
  int xcd = bid & 7, dir = (bid >> 3) & 1, q = bid >> 4;
  int b = xcd * 4 + q;
  int len = lens[b];
  int tid = threadIdx.x;            // 0..255
  int wv = tid >> 6, l = tid & 63;
  int j = wv * 32 + (l & 31);       // hidden unit 0..127
  int p = l >> 5;                   // K-half 0/1
  const float* gi = ws + OFF_GI + (size_t)b * SS * D3;

  // register-resident: 3 W_hh rows (r,z,n for unit j), K range [p*64, p*64+64)
  h2_t w0[32], w1[32], w2[32];
  {
    const float* r0 = whh + (size_t)j * HH + p * 64;
    const float* r1 = whh + (size_t)(j + 128) * HH + p * 64;
    const float* r2 = whh + (size_t)(j + 256) * HH + p * 64;
    #pragma unroll
    for (int k = 0; k < 32; ++k) {
      w0[k] = h2_t{(_Float16)r0[2 * k], (_Float16)r0[2 * k + 1]};
      w1[k] = h2_t{(_Float16)r1[2 * k], (_Float16)r1[2 * k + 1]};
      w2[k] = h2_t{(_Float16)r2[2 * k], (_Float16)r2[2 * k + 1]};
    }
  }
  float bh0 = bhh[j], bh1 = bhh[j + 128], bh2 = bhh[j + 256];

  __shared__ __align__(16) _Float16 hbuf[2][128];
  if (tid < 128) hbuf[0][tid] = (_Float16)0.0f;
  float h_own = 0.0f;

  float* outb = out + (size_t)b * SS * D2 + dir * HH;

#define K4_BAR() do {                                                          \
    asm volatile("s_waitcnt lgkmcnt(0)" ::: "memory");                         \
    __builtin_amdgcn_s_barrier();                                              \
    __builtin_amdgcn_sched_barrier(0);                                         \
  } while (0)

#define K4_PF(gx0, gx1, gx2, tnext) do {                                       \
    if (p == 0) {                                                              \
      int tp = (tnext) < len ? (tnext) : (len - 1);                            \
      int tgp = dir ? (len - 1 - tp) : tp;                                     \
      const float* gp = gi + (size_t)tgp * D3;                                 \
      gx0 = gp[j]; gx1 = gp[j + 128]; gx2 = gp[j + 256];                       \
    }                                                                          \
  } while (0)

  // one step: read h-half from hbuf[PB], 96 fdot2, shfl_xor(32) combine,
  // gates in p=0 lanes, write hbuf[PB^1] + out, prefetch t+4, one barrier.
#define K4_STEP(gx0, gx1, gx2, tstep, PB) do {                                 \
    const f16x8* hb8 = (const f16x8*)&hbuf[PB][p * 64];                        \
    float a00 = 0.f, a01 = 0.f, a02 = 0.f, a03 = 0.f;                          \
    float a10 = 0.f, a11 = 0.f, a12 = 0.f, a13 = 0.f;                          \
    float a20 = 0.f, a21 = 0.f, a22 = 0.f, a23 = 0.f;                          \
    _Pragma("unroll")                                                          \
    for (int k8 = 0; k8 < 8; ++k8) {                                           \
      f16x8 hv = hb8[k8];                                                      \
      h2_t q0 = __builtin_shufflevector(hv, hv, 0, 1);                         \
      h2_t q1 = __builtin_shufflevector(hv, hv, 2, 3);                         \
      h2_t q2 = __builtin_shufflevector(hv, hv, 4, 5);                         \
      h2_t q3 = __builtin_shufflevector(hv, hv, 6, 7);                         \
      a00 = __builtin_amdgcn_fdot2(q0, w0[4 * k8 + 0], a00, false);            \
      a01 = __builtin_amdgcn_fdot2(q1, w0[4 * k8 + 1], a01, false);            \
      a02 = __builtin_amdgcn_fdot2(q2, w0[4 * k8 + 2], a02, false);            \
      a03 = __builtin_amdgcn_fdot2(q3, w0[4 * k8 + 3], a03, false);            \
      a10 = __builtin_amdgcn_fdot2(q0, w1[4 * k8 + 0], a10, false);            \
      a11 = __builtin_amdgcn_fdot2(q1, w1[4 * k8 + 1], a11, false);            \
      a12 = __builtin_amdgcn_fdot2(q2, w1[4 * k8 + 2], a12, false);            \
      a13 = __builtin_amdgcn_fdot2(q3, w1[4 * k8 + 3], a13, false);            \
      a20 = __builtin_amdgcn_fdot2(q0, w2[4 * k8 + 0], a20, false);            \
      a21 = __builtin_amdgcn_fdot2(q1, w2[4 * k8 + 1], a21, false);            \
      a22 = __builtin_amdgcn_fdot2(q2, w2[4 * k8 + 2], a22, false);            \
      a23 = __builtin_amdgcn_fdot2(q3, w2[4 * k8 + 3], a23, false);            \
    }                                                                          \
    float s0 = ((a00 + a01) + (a02 + a03));                                    \
    float s1 = ((a10 + a11) + (a12 + a13));                                    \
    float s2 = ((a20 + a21) + (a22 + a23));                                    \
    s0 += __shfl_xor(s0, 32);                                                  \
    s1 += __shfl_xor(s1, 32);                                                  \
    s2 += __shfl_xor(s2, 32);                                                  \
    if (p == 0) {                                                              \
      float r = sigm((gx0) + s0 + bh0);                                        \
      float z = sigm((gx1) + s1 + bh1);                                        \
      float n = fast_tanh(fmaf(r, s2 + bh2, (gx2)));                           \
      float hn = (1.0f - z) * n + z * h_own;                                   \
      h_own = hn;                                                              \
      outb[(size_t)(tstep) * D2 + j] = hn;                                     \
      hbuf[(PB) ^ 1][j] = (_Float16)hn;                                        \
    }                                                                          \
    K4_PF(gx0, gx1, gx2, (tstep) + 4);                                         \
    K4_BAR();                                                                  \
  } while (0)

  // prologue: prefetch t=0..3 (len >= 256 always)
  float gA0 = 0.f, gA1 = 0.f, gA2 = 0.f;
  float gB0 = 0.f, gB1 = 0.f, gB2 = 0.f;
  float gC0 = 0.f, gC1 = 0.f, gC2 = 0.f;
  float gD0 = 0.f, gD1 = 0.f, gD2 = 0.f;
  K4_PF(gA0, gA1, gA2, 0);
  K4_PF(gB0, gB1, gB2, 1);
  K4_PF(gC0, gC1, gC2, 2);
  K4_PF(gD0, gD1, gD2, 3);
  K4_BAR();   // hbuf[0] init visible; global prefetches stay in flight

  int t = 0;
  while (t + 3 < len) {      // t stays a multiple of 4 -> parities 0,1,0,1
    K4_STEP(gA0, gA1, gA2, t,     0);
    K4_STEP(gB0, gB1, gB2, t + 1, 1);
    K4_STEP(gC0, gC1, gC2, t + 2, 0);
    K4_STEP(gD0, gD1, gD2, t + 3, 1);
    t += 4;
  }
  if (t < len)     K4_STEP(gA0, gA1, gA2, t,     0);
  if (t + 1 < len) K4_STEP(gB0, gB1, gB2, t + 1, 1);
  if (t + 2 < len) K4_STEP(gC0, gC1, gC2, t + 2, 0);

#undef K4_STEP
#undef K4_PF
#undef K4_BAR
}

extern "C" void kernel_launch(void* const* d_in, const int* in_sizes, int n_in,
                              void* d_out, int out_size, void* d_ws, size_t ws_size,
                              hipStream_t stream) {
  const float* vp   = (const float*)d_in[0];
  const int*   lens = (const int*)d_in[1];
  const float* Wvp  = (const float*)d_in[2];
  const float* Wvpt = (const float*)d_in[3];
  const float* wvt  = (const float*)d_in[4];
  const float* Wg   = (const float*)d_in[5];
  const float* Wih  = (const float*)d_in[6];
  const float* Whh  = (const float*)d_in[7];
  const float* bih  = (const float*)d_in[8];
  const float* bhh  = (const float*)d_in[9];
  float* out = (float*)d_out;
  float* ws  = (float*)d_ws;

  hipMemsetAsync(d_out, 0, (size_t)out_size * sizeof(float), stream);

  k0_prep<<<2048, 256, 0, stream>>>(Wg, Wih, Wvp, Wvpt, ws);
  k1_keyq<<<BB * SS / 64, 256, 0, stream>>>(vp, ws);
  k2_attn<<<1024, 256, 0, stream>>>(vp, lens, wvt, ws);
  k3_gates<<<dim3(SS / 32, BB), 256, 0, stream>>>(vp, lens, bih, ws);
  k4_scan<<<64, 256, 0, stream>>>(Whh, bhh, lens, ws, out);
}

// Round 13
// 526.911 us; speedup vs baseline: 1.4943x; 1.0096x over previous
//
#include <hip/hip_runtime.h>
#include <hip/hip_fp16.h>

#define BB 32
#define SS 512
#define HH 128
#define D2 256
#define D3 384
#define D4 512

// ws layout (float offsets)
#define OFF_TK  0                       // Ek = exp(2*keyp) TRANSPOSED [B][H][S] f32
#define OFF_TQ  (OFF_TK + BB*SS*HH)     // Eq = exp(2*q)    [B][S][H] f32
#define OFF_CT  (OFF_TQ + BB*SS*HH)     // context   [B][S][2H] f32
#define OFF_GI  (OFF_CT + BB*SS*D2)     // gi        [B][S][3H] f32
#define OFF_F16 (OFF_GI + BB*SS*D3)     // f16 weight region below (element offsets)
#define F16_WG  0                       // Wg  f16 [512][512] row-major (as given)
#define F16_WIH (F16_WG + D4*D4)        // Wih f16 [384][512]
#define F16_W2  (F16_WIH + D3*D4)       // [WvP;WvPt] f16 [256][256]

typedef _Float16 f16x8 __attribute__((ext_vector_type(8)));
typedef _Float16 f16x4 __attribute__((ext_vector_type(4)));
typedef float    f32x4 __attribute__((ext_vector_type(4)));
typedef _Float16 h2_t  __attribute__((ext_vector_type(2)));

__device__ __forceinline__ float fast_tanh(float x) {
  float ax = fabsf(x);
  float e  = __expf(-2.0f * ax);
  float t  = __fdividef(1.0f - e, 1.0f + e);
  return x < 0.0f ? -t : t;
}
__device__ __forceinline__ float sigm(float x) {
  return __fdividef(1.0f, 1.0f + __expf(-x));
}

// ---------------- K0: convert weights to f16 in ws ----------------
__global__ __launch_bounds__(256) void k0_prep(
    const float* __restrict__ Wg, const float* __restrict__ Wih,
    const float* __restrict__ Wvp, const float* __restrict__ Wvpt,
    float* __restrict__ ws) {
  int i = blockIdx.x * 256 + threadIdx.x;
  _Float16* f16b = (_Float16*)(ws + OFF_F16);
  if (i < D4 * D4) {
    f16b[F16_WG + i] = (_Float16)Wg[i];
  } else if (i < D4 * D4 + D3 * D4) {
    int j = i - D4 * D4;
    f16b[F16_WIH + j] = (_Float16)Wih[j];
  } else {
    int j = i - D4 * D4 - D3 * D4;   // < 65536
    f16b[F16_W2 + j] = (_Float16)(j < HH * D2 ? Wvp[j] : Wvpt[j - HH * D2]);
  }
}

// ---------------- K1: Ek^T / Eq = exp(2 * ([WvP;WvPt] . vp^T)) via MFMA ----------------
__global__ __launch_bounds__(256, 2) void k1_keyq(const float* __restrict__ vp,
                                                  float* __restrict__ ws) {
  __shared__ __align__(16) _Float16 vpH[64 * 256];
  int tid = threadIdx.x;
  int rows0 = blockIdx.x * 64;

  #pragma unroll
  for (int i = 0; i < 8; ++i) {
    int u = tid + i * 256;
    int r = u >> 5, c8 = u & 31;
    const float* src = vp + (size_t)(rows0 + r) * D2 + c8 * 8;
    float4 a = *(const float4*)src;
    float4 b = *(const float4*)(src + 4);
    f16x8 h;
    h[0]=(_Float16)a.x; h[1]=(_Float16)a.y; h[2]=(_Float16)a.z; h[3]=(_Float16)a.w;
    h[4]=(_Float16)b.x; h[5]=(_Float16)b.y; h[6]=(_Float16)b.z; h[7]=(_Float16)b.w;
    *(f16x8*)(&vpH[r * 256 + (c8 ^ (r & 7)) * 8]) = h;
  }
  __syncthreads();

  const _Float16* W2 = (const _Float16*)(ws + OFF_F16) + F16_W2;
  int w = tid >> 6, l = tid & 63;
  int lr = l & 15, lk = (l >> 4) * 8;

  f32x4 acc[4][4];
  #pragma unroll
  for (int m = 0; m < 4; ++m)
    #pragma unroll
    for (int n = 0; n < 4; ++n) acc[m][n] = (f32x4){0.f, 0.f, 0.f, 0.f};

  for (int kc = 0; kc < 8; ++kc) {
    int k = kc * 32 + lk;
    f16x8 bf[4];
    #pragma unroll
    for (int n = 0; n < 4; ++n) {
      int r = n * 16 + lr;
      bf[n] = *(const f16x8*)(&vpH[r * 256 + (((k >> 3) ^ (r & 7))) * 8]);
    }
    #pragma unroll
    for (int m = 0; m < 4; ++m) {
      int c = w * 64 + m * 16 + lr;
      f16x8 af = *(const f16x8*)(W2 + (size_t)c * 256 + k);
      #pragma unroll
      for (int n = 0; n < 4; ++n)
        acc[m][n] = __builtin_amdgcn_mfma_f32_16x16x32_f16(af, bf[n], acc[m][n], 0, 0, 0);
    }
  }

  int b = rows0 >> 9;          // batch
  int s0 = rows0 & 511;        // s offset within batch
  float* ekT = ws + OFF_TK + (size_t)b * HH * SS;
  float* eqp = ws + OFF_TQ + (size_t)b * SS * HH;
  #pragma unroll
  for (int m = 0; m < 4; ++m) {
    int c0 = w * 64 + m * 16 + (l >> 4) * 4;
    #pragma unroll
    for (int n = 0; n < 4; ++n) {
      int s = s0 + n * 16 + lr;
      float v[4];
      #pragma unroll
      for (int j = 0; j < 4; ++j) {
        float z = fminf(fmaxf(2.0f * acc[m][n][j], -60.0f), 60.0f);
        v[j] = __expf(z);
      }
      if (c0 < HH) {
        // Ek transposed: [h][s]
        #pragma unroll
        for (int j = 0; j < 4; ++j)
          ekT[(size_t)(c0 + j) * SS + s] = v[j];
      } else {
        float4 o; o.x = v[0]; o.y = v[1]; o.z = v[2]; o.w = v[3];
        *(float4*)(eqp + (size_t)s * HH + (c0 - HH)) = o;
      }
    }
  }
}

// ---------------- K2: logits via exp-form tanh + softmax + ct ----------------
// 1-D grid 1024 blocks: bid = [t:5][q:2][xcd:3]; all 32 t-tiles of batch b
// share one XCD. L stored as f16 t-pairs (16KB) + Eqs f32 (8KB) -> 24.4KB LDS.
// Trans-issue-bound (~1.07e9 v_rcp = ~109us chip floor); at ~114% of floor.
__global__ __launch_bounds__(256) void k2_attn(const float* __restrict__ vp,
                                               const int* __restrict__ lens,
                                               const float* __restrict__ wvt,
                                               float* __restrict__ ws) {
  int bid = blockIdx.x;                 // 0..1023
  int b  = (bid & 7) * 4 + ((bid >> 3) & 3);
  int t0 = (bid >> 5) * 16;             // 0..496
  int len = lens[b];
  if (t0 >= len) return;
  int nt = min(16, len - t0);

  __shared__ __align__(16) _Float16 Lh[8][SS][2];  // [t/2][s][t&1], 16KB
  __shared__ __align__(16) float Eqs[16][HH];      // 8KB
  __shared__ float inv_sum[16];

  int tid = threadIdx.x;
  const float* EkT = ws + OFF_TK + (size_t)b * HH * SS;
  const float* Eqg = ws + OFF_TQ + ((size_t)b * SS + t0) * HH;

  // stage Eq tile (16 x 128 f32) into LDS, vectorized
  for (int idx = tid; idx < 16 * HH / 4; idx += 256) {
    int i = idx >> 5, h4 = idx & 31;
    *(float4*)&Eqs[i][h4 * 4] = *(const float4*)(Eqg + (size_t)i * HH + h4 * 4);
  }
  __syncthreads();

  // logits: tanh(k+q) = 1 - 2/(Ek*Eq+1); softmax shift-invariance drops the
  // constant sum(w) term -> L = -2 * sum_h w_h * rcp(Ek*Eq+1).
  // Thread owns s-cols {tid, tid+256}; s0 < 256 <= len always valid.
  {
    int s0 = tid, s1 = tid + 256;
    float acc0[16] = {}, acc1[16] = {};
    for (int h4 = 0; h4 < 32; ++h4) {
      const float* ek = EkT + (size_t)(h4 * 4) * SS;
      float ka0 = ek[s0],          kb0 = ek[s1];
      float ka1 = ek[SS + s0],     kb1 = ek[SS + s1];
      float ka2 = ek[2 * SS + s0], kb2 = ek[2 * SS + s1];
      float ka3 = ek[3 * SS + s0], kb3 = ek[3 * SS + s1];
      const float4 w4 = *(const float4*)(wvt + h4 * 4);
      #pragma unroll
      for (int t = 0; t < 16; ++t) {
        const float4 q4 = *(const float4*)(&Eqs[t][h4 * 4]);
        float r0 = __builtin_amdgcn_rcpf(fmaf(ka0, q4.x, 1.0f));
        float r1 = __builtin_amdgcn_rcpf(fmaf(ka1, q4.y, 1.0f));
        float r2 = __builtin_amdgcn_rcpf(fmaf(ka2, q4.z, 1.0f));
        float r3 = __builtin_amdgcn_rcpf(fmaf(ka3, q4.w, 1.0f));
        float u0 = __builtin_amdgcn_rcpf(fmaf(kb0, q4.x, 1.0f));
        float u1 = __builtin_amdgcn_rcpf(fmaf(kb1, q4.y, 1.0f));
        float u2 = __builtin_amdgcn_rcpf(fmaf(kb2, q4.z, 1.0f));
        float u3 = __builtin_amdgcn_rcpf(fmaf(kb3, q4.w, 1.0f));
        float a = acc0[t];
        a = fmaf(w4.x, r0, a);
        a = fmaf(w4.y, r1, a);
        a = fmaf(w4.z, r2, a);
        a = fmaf(w4.w, r3, a);
        acc0[t] = a;
        float c = acc1[t];
        c = fmaf(w4.x, u0, c);
        c = fmaf(w4.y, u1, c);
        c = fmaf(w4.z, u2, c);
        c = fmaf(w4.w, u3, c);
        acc1[t] = c;
      }
    }
    #pragma unroll
    for (int tp = 0; tp < 8; ++tp) {
      h2_t v0, v1;
      v0[0] = (_Float16)(-2.0f * acc0[2 * tp]);
      v0[1] = (_Float16)(-2.0f * acc0[2 * tp + 1]);
      v1[0] = (_Float16)(-2.0f * acc1[2 * tp]);
      v1[1] = (_Float16)(-2.0f * acc1[2 * tp + 1]);
      *(h2_t*)&Lh[tp][s0][0] = v0;
      *(h2_t*)&Lh[tp][s1][0] = v1;
    }
  }
  __syncthreads();

  // softmax (store unnormalized exp as f16; denominators in inv_sum)
  {
    int w = tid >> 6, lane = tid & 63;
    for (int ii = 0; ii < 4; ++ii) {
      int i = w + ii * 4;
      if (i < nt) {
        int ip = i >> 1, il = i & 1;
        float m = -1e30f;
        for (int s = lane; s < len; s += 64) m = fmaxf(m, (float)Lh[ip][s][il]);
        #pragma unroll
        for (int off = 32; off > 0; off >>= 1) m = fmaxf(m, __shfl_xor(m, off));
        float sm = 0.0f;
        for (int s = lane; s < len; s += 64) {
          float e = __expf((float)Lh[ip][s][il] - m);
          Lh[ip][s][il] = (_Float16)e;
          sm += e;
        }
        #pragma unroll
        for (int off = 32; off > 0; off >>= 1) sm += __shfl_xor(sm, off);
        if (lane == 0) inv_sum[i] = __fdividef(1.0f, sm);
      }
    }
  }
  __syncthreads();

  // ct[t][d] = sum_s p[t][s] * vp[b][s][d]  (vp from L2; p reads are
  // wave-uniform f16x2 LDS broadcasts: 2 reads serve 4 t's)
  int d4 = (tid & 63) * 4;
  int tg = tid >> 6;
  float4 acc4[4] = {};
  const float* vpb = vp + (size_t)b * SS * D2;
  int s = 0;
  for (; s + 4 <= len; s += 4) {
    #pragma unroll
    for (int u = 0; u < 4; ++u) {
      float4 v4 = *(const float4*)(vpb + (size_t)(s + u) * D2 + d4);
      h2_t pA = *(const h2_t*)&Lh[tg * 2][s + u][0];      // t = 4tg, 4tg+1
      h2_t pB = *(const h2_t*)&Lh[tg * 2 + 1][s + u][0];  // t = 4tg+2, 4tg+3
      float p0 = (float)pA[0], p1 = (float)pA[1];
      float p2 = (float)pB[0], p3 = (float)pB[1];
      acc4[0].x = fmaf(p0, v4.x, acc4[0].x);
      acc4[0].y = fmaf(p0, v4.y, acc4[0].y);
      acc4[0].z = fmaf(p0, v4.z, acc4[0].z);
      acc4[0].w = fmaf(p0, v4.w, acc4[0].w);
      acc4[1].x = fmaf(p1, v4.x, acc4[1].x);
      acc4[1].y = fmaf(p1, v4.y, acc4[1].y);
      acc4[1].z = fmaf(p1, v4.z, acc4[1].z);
      acc4[1].w = fmaf(p1, v4.w, acc4[1].w);
      acc4[2].x = fmaf(p2, v4.x, acc4[2].x);
      acc4[2].y = fmaf(p2, v4.y, acc4[2].y);
      acc4[2].z = fmaf(p2, v4.z, acc4[2].z);
      acc4[2].w = fmaf(p2, v4.w, acc4[2].w);
      acc4[3].x = fmaf(p3, v4.x, acc4[3].x);
      acc4[3].y = fmaf(p3, v4.y, acc4[3].y);
      acc4[3].z = fmaf(p3, v4.z, acc4[3].z);
      acc4[3].w = fmaf(p3, v4.w, acc4[3].w);
    }
  }
  for (; s < len; ++s) {
    float4 v4 = *(const float4*)(vpb + (size_t)s * D2 + d4);
    h2_t pA = *(const h2_t*)&Lh[tg * 2][s][0];
    h2_t pB = *(const h2_t*)&Lh[tg * 2 + 1][s][0];
    float pj[4] = {(float)pA[0], (float)pA[1], (float)pB[0], (float)pB[1]};
    #pragma unroll
    for (int j = 0; j < 4; ++j) {
      acc4[j].x = fmaf(pj[j], v4.x, acc4[j].x);
      acc4[j].y = fmaf(pj[j], v4.y, acc4[j].y);
      acc4[j].z = fmaf(pj[j], v4.z, acc4[j].z);
      acc4[j].w = fmaf(pj[j], v4.w, acc4[j].w);
    }
  }
  float* ctg = ws + OFF_CT + ((size_t)b * SS + t0) * D2;
  #pragma unroll
  for (int j = 0; j < 4; ++j) {
    int t = tg * 4 + j;
    if (t < nt) {
      float is = inv_sum[t];
      float4 o;
      o.x = acc4[j].x * is; o.y = acc4[j].y * is;
      o.z = acc4[j].z * is; o.w = acc4[j].w * is;
      *(float4*)(ctg + (size_t)t * D2 + d4) = o;
    }
  }
}

// ---------------- K3: gt' = Wg.vpc^T -> xin (in-place LDS) -> gi' = Wih.xin^T ----------------
__global__ __launch_bounds__(256, 2) void k3_gates(const float* __restrict__ vp,
                                                   const int* __restrict__ lens,
                                                   const float* __restrict__ bih,
                                                   float* __restrict__ ws) {
  int b = blockIdx.y;
  int len = lens[b];
  int t0 = blockIdx.x * 32;
  if (t0 >= len) return;

  __shared__ __align__(16) _Float16 vpcH[32 * 512];
  int tid = threadIdx.x;
  const float* ct = ws + OFF_CT;

  #pragma unroll
  for (int i = 0; i < 8; ++i) {
    int u = tid + i * 256;
    int r = u >> 6, c8 = u & 63;
    int c = c8 * 8;
    const float* src = (c < D2) ? (vp + ((size_t)b * SS + t0 + r) * D2 + c)
                                : (ct + ((size_t)b * SS + t0 + r) * D2 + (c - D2));
    float4 a = *(const float4*)src;
    float4 bb = *(const float4*)(src + 4);
    f16x8 h;
    h[0]=(_Float16)a.x;  h[1]=(_Float16)a.y;  h[2]=(_Float16)a.z;  h[3]=(_Float16)a.w;
    h[4]=(_Float16)bb.x; h[5]=(_Float16)bb.y; h[6]=(_Float16)bb.z; h[7]=(_Float16)bb.w;
    *(f16x8*)(&vpcH[r * 512 + (c8 ^ (r & 7)) * 8]) = h;
  }
  __syncthreads();

  const _Float16* WgH  = (const _Float16*)(ws + OFF_F16) + F16_WG;
  const _Float16* WihH = (const _Float16*)(ws + OFF_F16) + F16_WIH;
  int w = tid >> 6, l = tid & 63;
  int lr = l & 15, lk = (l >> 4) * 8;

  f32x4 acc[8][2];
  #pragma unroll
  for (int m = 0; m < 8; ++m) { acc[m][0] = (f32x4){0.f,0.f,0.f,0.f}; acc[m][1] = (f32x4){0.f,0.f,0.f,0.f}; }

  for (int kc = 0; kc < 16; ++kc) {
    int k = kc * 32 + lk;
    f16x8 bf[2];
    #pragma unroll
    for (int n = 0; n < 2; ++n) {
      int r = n * 16 + lr;
      bf[n] = *(const f16x8*)(&vpcH[r * 512 + (((k >> 3) ^ (r & 7))) * 8]);
    }
    #pragma unroll
    for (int m = 0; m < 8; ++m) {
      int c = w * 128 + m * 16 + lr;
      f16x8 af = *(const f16x8*)(WgH + (size_t)c * 512 + k);
      acc[m][0] = __builtin_amdgcn_mfma_f32_16x16x32_f16(af, bf[0], acc[m][0], 0, 0, 0);
      acc[m][1] = __builtin_amdgcn_mfma_f32_16x16x32_f16(af, bf[1], acc[m][1], 0, 0, 0);
    }
  }

  f16x4 xq[8][2];
  #pragma unroll
  for (int m = 0; m < 8; ++m) {
    int c0 = w * 128 + m * 16 + (l >> 4) * 4;
    #pragma unroll
    for (int n = 0; n < 2; ++n) {
      int r = n * 16 + lr;
      int ea = r * 512 + (((c0 >> 3) ^ (r & 7))) * 8 + (c0 & 7);
      f16x4 vq = *(const f16x4*)(&vpcH[ea]);
      f16x4 xo;
      #pragma unroll
      for (int j = 0; j < 4; ++j)
        xo[j] = (_Float16)(sigm(acc[m][n][j]) * (float)vq[j]);
      xq[m][n] = xo;
    }
  }
  __syncthreads();
  #pragma unroll
  for (int m = 0; m < 8; ++m) {
    int c0 = w * 128 + m * 16 + (l >> 4) * 4;
    #pragma unroll
    for (int n = 0; n < 2; ++n) {
      int r = n * 16 + lr;
      int ea = r * 512 + (((c0 >> 3) ^ (r & 7))) * 8 + (c0 & 7);
      *(f16x4*)(&vpcH[ea]) = xq[m][n];
    }
  }
  __syncthreads();

  f32x4 gacc[6][2];
  #pragma unroll
  for (int m = 0; m < 6; ++m) { gacc[m][0] = (f32x4){0.f,0.f,0.f,0.f}; gacc[m][1] = (f32x4){0.f,0.f,0.f,0.f}; }

  for (int kc = 0; kc < 16; ++kc) {
    int k = kc * 32 + lk;
    f16x8 bf[2];
    #pragma unroll
    for (int n = 0; n < 2; ++n) {
      int r = n * 16 + lr;
      bf[n] = *(const f16x8*)(&vpcH[r * 512 + (((k >> 3) ^ (r & 7))) * 8]);
    }
    #pragma unroll
    for (int m = 0; m < 6; ++m) {
      int c = w * 96 + m * 16 + lr;
      f16x8 af = *(const f16x8*)(WihH + (size_t)c * 512 + k);
      gacc[m][0] = __builtin_amdgcn_mfma_f32_16x16x32_f16(af, bf[0], gacc[m][0], 0, 0, 0);
      gacc[m][1] = __builtin_amdgcn_mfma_f32_16x16x32_f16(af, bf[1], gacc[m][1], 0, 0, 0);
    }
  }

  float* gig = ws + OFF_GI;
  #pragma unroll
  for (int m = 0; m < 6; ++m) {
    int c0 = w * 96 + m * 16 + (l >> 4) * 4;
    float4 bq = *(const float4*)(bih + c0);
    #pragma unroll
    for (int n = 0; n < 2; ++n) {
      int r = n * 16 + lr;
      float4 o;
      o.x = gacc[m][n][0] + bq.x;
      o.y = gacc[m][n][1] + bq.y;
      o.z = gacc[m][n][2] + bq.z;
      o.w = gacc[m][n][3] + bq.w;
      *(float4*)(gig + ((size_t)b * SS + t0 + r) * D3 + c0) = o;
    }
  }
}

// ---------------- K4: GRU scan (R7 structure, + pointer-increment prefetch
// and epilogue zero-fill replacing the out memset). 256 threads, pair-split K
// (lane l: unit j = 32*wave + (l&31), K-half p = l>>5). 96 weight VGPRs,
// shfl_xor(32) combine, double-buffered hbuf, ONE barrier/step, depth-4 gi
// prefetch via loop-carried pointer (no per-step address math). ----------
__global__ __launch_bounds__(256, 1) void k4_scan(const float* __restrict__ whh,
                                                  const float* __restrict__ bhh,
                                                  const int* __restrict__ lens,
                                                  const float* __restrict__ ws,
                                                  float* __restrict__ out) {
  int bid = blockIdx.x;
  // XCD-pair swizzle: fwd/rev of same b land on the same XCD (bid%8 preserved)
  int xcd = bid & 7, dir = (bid >> 3) & 1, q = bid >> 4;
  int b = xcd * 4 + q;
  int len = lens[b];
  int tid = threadIdx.x;            // 0..255
  int wv = tid >> 6, l = tid & 63;
  int j = wv * 32 + (l & 31);       // hidden unit 0..127
  int p = l >> 5;                   // K-half 0/1
  const float* gi = ws + OFF_GI + (size_t)b * SS * D3;

  // register-resident: 3 W_hh rows (r,z,n for unit j), K range [p*64, p*64+64)
  h2_t w0[32], w1[32], w2[32];
  {
    const float* r0 = whh + (size_t)j * HH + p * 64;
    const float* r1 = whh + (size_t)(j + 128) * HH + p * 64;
    const float* r2 = whh + (size_t)(j + 256) * HH + p * 64;
    #pragma unroll
    for (int k = 0; k < 32; ++k) {
      w0[k] = h2_t{(_Float16)r0[2 * k], (_Float16)r0[2 * k + 1]};
      w1[k] = h2_t{(_Float16)r1[2 * k], (_Float16)r1[2 * k + 1]};
      w2[k] = h2_t{(_Float16)r2[2 * k], (_Float16)r2[2 * k + 1]};
    }
  }
  float bh0 = bhh[j], bh1 = bhh[j + 128], bh2 = bhh[j + 256];

  __shared__ __align__(16) _Float16 hbuf[2][128];
  if (tid < 128) hbuf[0][tid] = (_Float16)0.0f;
  float h_own = 0.0f;

  float* outb = out + (size_t)b * SS * D2 + dir * HH;
  const int stride = dir ? -D3 : D3;
  // loop-carried prefetch pointer: row for t=4 (len >= 256 so len-5 >= 0).
  // Overshoot in the last <=4 steps reads in-bounds ws garbage, never consumed.
  const float* gp = gi + (size_t)(dir ? (len - 5) : 4) * D3;

#define K4_BAR() do {                                                          \
    asm volatile("s_waitcnt lgkmcnt(0)" ::: "memory");                         \
    __builtin_amdgcn_s_barrier();                                              \
    __builtin_amdgcn_sched_barrier(0);                                         \
  } while (0)

  // prologue-only: explicit row for step tt (tt < len guaranteed)
#define K4_PF_AT(gx0, gx1, gx2, tt) do {                                       \
    if (p == 0) {                                                              \
      int tgp = dir ? (len - 1 - (tt)) : (tt);                                 \
      const float* gq = gi + (size_t)tgp * D3;                                 \
      gx0 = gq[j]; gx1 = gq[j + 128]; gx2 = gq[j + 256];                       \
    }                                                                          \
  } while (0)

  // steady-state: load from loop-carried pointer, then advance
#define K4_PF_PTR(gx0, gx1, gx2) do {                                          \
    if (p == 0) {                                                              \
      gx0 = gp[j]; gx1 = gp[j + 128]; gx2 = gp[j + 256];                       \
    }                                                                          \
    gp += stride;                                                              \
  } while (0)

  // one step: read h-half from hbuf[PB], 96 fdot2, shfl_xor(32) combine,
  // gates in p=0 lanes, write hbuf[PB^1] + out, prefetch (ptr), one barrier.
#define K4_STEP(gx0, gx1, gx2, tstep, PB) do {                                 \
    const f16x8* hb8 = (const f16x8*)&hbuf[PB][p * 64];                        \
    float a00 = 0.f, a01 = 0.f, a02 = 0.f, a03 = 0.f;                          \
    float a10 = 0.f, a11 = 0.f, a12 = 0.f, a13 = 0.f;                          \
    float a20 = 0.f, a21 = 0.f, a22 = 0.f, a23 = 0.f;                          \
    _Pragma("unroll")                                                          \
    for (int k8 = 0; k8 < 8; ++k8) {                                           \
      f16x8 hv = hb8[k8];                                                      \
      h2_t q0 = __builtin_shufflevector(hv, hv, 0, 1);                         \
      h2_t q1 = __builtin_shufflevector(hv, hv, 2, 3);                         \
      h2_t q2 = __builtin_shufflevector(hv, hv, 4, 5);                         \
      h2_t q3 = __builtin_shufflevector(hv, hv, 6, 7);                         \
      a00 = __builtin_amdgcn_fdot2(q0, w0[4 * k8 + 0], a00, false);            \
      a01 = __builtin_amdgcn_fdot2(q1, w0[4 * k8 + 1], a01, false);            \
      a02 = __builtin_amdgcn_fdot2(q2, w0[4 * k8 + 2], a02, false);            \
      a03 = __builtin_amdgcn_fdot2(q3, w0[4 * k8 + 3], a03, false);            \
      a10 = __builtin_amdgcn_fdot2(q0, w1[4 * k8 + 0], a10, false);            \
      a11 = __builtin_amdgcn_fdot2(q1, w1[4 * k8 + 1], a11, false);            \
      a12 = __builtin_amdgcn_fdot2(q2, w1[4 * k8 + 2], a12, false);            \
      a13 = __builtin_amdgcn_fdot2(q3, w1[4 * k8 + 3], a13, false);            \
      a20 = __builtin_amdgcn_fdot2(q0, w2[4 * k8 + 0], a20, false);            \
      a21 = __builtin_amdgcn_fdot2(q1, w2[4 * k8 + 1], a21, false);            \
      a22 = __builtin_amdgcn_fdot2(q2, w2[4 * k8 + 2], a22, false);            \
      a23 = __builtin_amdgcn_fdot2(q3, w2[4 * k8 + 3], a23, false);            \
    }                                                                          \
    float s0 = ((a00 + a01) + (a02 + a03));                                    \
    float s1 = ((a10 + a11) + (a12 + a13));                                    \
    float s2 = ((a20 + a21) + (a22 + a23));                                    \
    s0 += __shfl_xor(s0, 32);                                                  \
    s1 += __shfl_xor(s1, 32);                                                  \
    s2 += __shfl_xor(s2, 32);                                                  \
    if (p == 0) {                                                              \
      float r = sigm((gx0) + s0 + bh0);                                        \
      float z = sigm((gx1) + s1 + bh1);                                        \
      float n = fast_tanh(fmaf(r, s2 + bh2, (gx2)));                           \
      float hn = (1.0f - z) * n + z * h_own;                                   \
      h_own = hn;                                                              \
      outb[(size_t)(tstep) * D2 + j] = hn;                                     \
      hbuf[(PB) ^ 1][j] = (_Float16)hn;                                        \
    }                                                                          \
    K4_PF_PTR(gx0, gx1, gx2);                                                  \
    K4_BAR();                                                                  \
  } while (0)

  // prologue: prefetch t=0..3 (len >= 256 always)
  float gA0 = 0.f, gA1 = 0.f, gA2 = 0.f;
  float gB0 = 0.f, gB1 = 0.f, gB2 = 0.f;
  float gC0 = 0.f, gC1 = 0.f, gC2 = 0.f;
  float gD0 = 0.f, gD1 = 0.f, gD2 = 0.f;
  K4_PF_AT(gA0, gA1, gA2, 0);
  K4_PF_AT(gB0, gB1, gB2, 1);
  K4_PF_AT(gC0, gC1, gC2, 2);
  K4_PF_AT(gD0, gD1, gD2, 3);
  K4_BAR();   // hbuf[0] init visible; global prefetches stay in flight

  int t = 0;
  while (t + 3 < len) {      // t stays a multiple of 4 -> parities 0,1,0,1
    K4_STEP(gA0, gA1, gA2, t,     0);
    K4_STEP(gB0, gB1, gB2, t + 1, 1);
    K4_STEP(gC0, gC1, gC2, t + 2, 0);
    K4_STEP(gD0, gD1, gD2, t + 3, 1);
    t += 4;
  }
  if (t < len)     K4_STEP(gA0, gA1, gA2, t,     0);
  if (t + 1 < len) K4_STEP(gB0, gB1, gB2, t + 1, 1);
  if (t + 2 < len) K4_STEP(gC0, gC1, gC2, t + 2, 0);

  // epilogue: zero the padded rows [len, SS) of this (b,dir) output half.
  // Replaces the global hipMemsetAsync; runs while other blocks still scan.
  if (p == 0) {
    for (int tt = len; tt < SS; ++tt)
      outb[(size_t)tt * D2 + j] = 0.0f;
  }

#undef K4_STEP
#undef K4_PF_PTR
#undef K4_PF_AT
#undef K4_BAR
}

extern "C" void kernel_launch(void* const* d_in, const int* in_sizes, int n_in,
                              void* d_out, int out_size, void* d_ws, size_t ws_size,
                              hipStream_t stream) {
  const float* vp   = (const float*)d_in[0];
  const int*   lens = (const int*)d_in[1];
  const float* Wvp  = (const float*)d_in[2];
  const float* Wvpt = (const float*)d_in[3];
  const float* wvt  = (const float*)d_in[4];
  const float* Wg   = (const float*)d_in[5];
  const float* Wih  = (const float*)d_in[6];
  const float* Whh  = (const float*)d_in[7];
  const float* bih  = (const float*)d_in[8];
  const float* bhh  = (const float*)d_in[9];
  float* out = (float*)d_out;
  float* ws  = (float*)d_ws;

  k0_prep<<<2048, 256, 0, stream>>>(Wg, Wih, Wvp, Wvpt, ws);
  k1_keyq<<<BB * SS / 64, 256, 0, stream>>>(vp, ws);
  k2_attn<<<1024, 256, 0, stream>>>(vp, lens, wvt, ws);
  k3_gates<<<dim3(SS / 32, BB), 256, 0, stream>>>(vp, lens, bih, ws);
  k4_scan<<<64, 256, 0, stream>>>(Whh, bhh, lens, ws, out);
}